// Round 3
// baseline (954.905 us; speedup 1.0000x reference)
//
#include <hip/hip_runtime.h>
#include <hip/hip_bf16.h>

// GCN graph classifier: 3x (GCNConv -> BN -> ReLU) -> sum-pool -> MLP head.
//   Hs[i] = (x[i]@W.T + b) * rdeg[i]           (gemm, reads X^T coalesced)
//   V[d]  = rdeg[d]*(Hs[d] + sum_in Hs[s])     (CSR gather, no atomics)
//   X     = relu(a*V + b2)                     (BN fold; written transposed for next gemm)
// Pool = segmented sum over sorted batch (binary search bounds, no atomics).

#define NN 100000
#define NE 1600000
#define INF_ 128
#define HF 64
#define OUTF 10
#define NG 128

__global__ void k_hist(const int* __restrict__ dst, int* __restrict__ cnt, int E) {
    int e = blockIdx.x * 256 + threadIdx.x;
    if (e < E) atomicAdd(&cnt[dst[e]], 1);
}

__global__ void k_rdegi(const int* __restrict__ cnt, float* __restrict__ rdeg, int n) {
    int i = blockIdx.x * 256 + threadIdx.x;
    if (i < n) rdeg[i] = rsqrtf((float)cnt[i] + 1.0f);  // +1 = self loop
}

__global__ void k_scan1(const int* __restrict__ cnt, int* __restrict__ ro,
                        int* __restrict__ bsum, int n) {
    __shared__ int ts[256];
    int base = blockIdx.x * 1024 + threadIdx.x * 4;
    int v[4], s = 0;
#pragma unroll
    for (int k = 0; k < 4; ++k) {
        int idx = base + k;
        v[k] = (idx < n) ? cnt[idx] : 0;
        s += v[k];
    }
    ts[threadIdx.x] = s;
    __syncthreads();
    for (int off = 1; off < 256; off <<= 1) {
        int t = (threadIdx.x >= off) ? ts[threadIdx.x - off] : 0;
        __syncthreads();
        ts[threadIdx.x] += t;
        __syncthreads();
    }
    int ex = ts[threadIdx.x] - s;
    if (threadIdx.x == 255) bsum[blockIdx.x] = ts[255];
#pragma unroll
    for (int k = 0; k < 4; ++k) {
        int idx = base + k;
        if (idx < n) ro[idx] = ex;
        ex += v[k];
    }
}

__global__ void k_scan2(int* __restrict__ bsum, int nb) {
    __shared__ int ts[128];
    int i = threadIdx.x;
    int v = (i < nb) ? bsum[i] : 0;
    ts[i] = v;
    __syncthreads();
    for (int off = 1; off < 128; off <<= 1) {
        int t = (i >= off) ? ts[i - off] : 0;
        __syncthreads();
        ts[i] += t;
        __syncthreads();
    }
    if (i < nb) bsum[i] = ts[i] - v;
}

__global__ void k_scan3(int* __restrict__ ro, int* __restrict__ cursor,
                        const int* __restrict__ bsum, int n, int E) {
    int i = blockIdx.x * 256 + threadIdx.x;
    if (i < n) {
        int v = ro[i] + bsum[i >> 10];
        ro[i] = v;
        cursor[i] = v;
    }
    if (i == 0) ro[n] = E;
}

__global__ void k_scatter(const int* __restrict__ src, const int* __restrict__ dst,
                          int* __restrict__ cursor, int* __restrict__ ss, int E) {
    int e = blockIdx.x * 256 + threadIdx.x;
    if (e < E) {
        int pos = atomicAdd(&cursor[dst[e]], 1);
        ss[pos] = src[e];
    }
}

// LDS 64x64 tile transpose: X [n][C] -> XT [C][n]. Grid (ceil(n/64), C/64).
__global__ __launch_bounds__(256) void k_xpose(const float* __restrict__ X,
                                               float* __restrict__ XT, int n, int C) {
    __shared__ float t[64][65];
    int r0 = blockIdx.x * 64, c0 = blockIdx.y * 64;
    int c = threadIdx.x & 63, rr = threadIdx.x >> 6;
#pragma unroll
    for (int i = 0; i < 16; ++i) {
        int r = r0 + i * 4 + rr;
        if (r < n) t[i * 4 + rr][c] = X[(size_t)r * C + c0 + c];
    }
    __syncthreads();
    int r = r0 + c;
#pragma unroll
    for (int i = 0; i < 16; ++i) {
        int cc = i * 4 + rr;
        if (r < n) XT[(size_t)(c0 + cc) * n + r] = t[c][cc];
    }
}

// Thread-per-row GEMM, X^T input (lane=row -> coalesced b32 loads), W via s_load.
template<int K>
__global__ __launch_bounds__(256) void k_gemm_t(const float* __restrict__ XT,
                                                const float* __restrict__ W,
                                                const float* __restrict__ bias,
                                                const float* __restrict__ rdeg,
                                                float* __restrict__ Hs, int n) {
    int row = blockIdx.x * 256 + threadIdx.x;
    if (row >= n) return;
    float acc[HF];
#pragma unroll
    for (int o = 0; o < HF; ++o) acc[o] = 0.f;
    const float* xp = XT + row;
    for (int kk = 0; kk < K; kk += 8) {
        float xv[8];
#pragma unroll
        for (int j = 0; j < 8; ++j) xv[j] = xp[(size_t)(kk + j) * n];
#pragma unroll
        for (int o = 0; o < HF; ++o) {
            float a = acc[o];
            const float* wr = W + o * K + kk;
#pragma unroll
            for (int j = 0; j < 8; ++j) a = fmaf(xv[j], wr[j], a);
            acc[o] = a;
        }
    }
    float r = rdeg[row];
    float4* hs = (float4*)(Hs + (size_t)row * HF);
#pragma unroll
    for (int o = 0; o < HF; o += 4)
        hs[o >> 2] = make_float4((bias[o] + acc[o]) * r, (bias[o + 1] + acc[o + 1]) * r,
                                 (bias[o + 2] + acc[o + 2]) * r, (bias[o + 3] + acc[o + 3]) * r);
}

// Fallback gemm (row-major X input) for thin-workspace path.
template<int K>
__global__ __launch_bounds__(256) void k_gemm(const float* __restrict__ X,
                                              const float* __restrict__ W,
                                              const float* __restrict__ bias,
                                              const float* __restrict__ rdeg,
                                              float* __restrict__ Hs, int n) {
    int row = blockIdx.x * 256 + threadIdx.x;
    if (row >= n) return;
    float acc[HF];
#pragma unroll
    for (int o = 0; o < HF; ++o) acc[o] = 0.f;
    const float* xr = X + (size_t)row * K;
    for (int kk = 0; kk < K; kk += 4) {
        float4 xv = *(const float4*)(xr + kk);
#pragma unroll
        for (int o = 0; o < HF; ++o) {
            float4 wv = *(const float4*)(W + o * K + kk);
            acc[o] = fmaf(xv.x, wv.x, fmaf(xv.y, wv.y, fmaf(xv.z, wv.z, fmaf(xv.w, wv.w, acc[o]))));
        }
    }
    float r = rdeg[row];
    float4* hs = (float4*)(Hs + (size_t)row * HF);
#pragma unroll
    for (int o = 0; o < HF; o += 4)
        hs[o >> 2] = make_float4((bias[o] + acc[o]) * r, (bias[o + 1] + acc[o + 1]) * r,
                                 (bias[o + 2] + acc[o + 2]) * r, (bias[o + 3] + acc[o + 3]) * r);
}

// One wave per node, lane = channel. V = rdeg*(Hs[self] + sum Hs[src]).
__global__ __launch_bounds__(256) void k_agg(const int* __restrict__ ro,
                                             const int* __restrict__ ss,
                                             const float* __restrict__ Hs,
                                             const float* __restrict__ rdeg,
                                             float* __restrict__ V, int n) {
    int node = blockIdx.x * 4 + (threadIdx.x >> 6);
    if (node >= n) return;
    int lane = threadIdx.x & 63;
    int beg = ro[node], end = ro[node + 1];
    float acc = Hs[(size_t)node * HF + lane];
    int j = beg;
    for (; j + 3 < end; j += 4) {
        int s0 = ss[j], s1 = ss[j + 1], s2 = ss[j + 2], s3 = ss[j + 3];
        float v0 = Hs[(size_t)s0 * HF + lane];
        float v1 = Hs[(size_t)s1 * HF + lane];
        float v2 = Hs[(size_t)s2 * HF + lane];
        float v3 = Hs[(size_t)s3 * HF + lane];
        acc += v0 + v1 + v2 + v3;
    }
    for (; j < end; ++j) acc += Hs[(size_t)ss[j] * HF + lane];
    V[(size_t)node * HF + lane] = rdeg[node] * acc;
}

__global__ void k_stats(const float* __restrict__ V, float* __restrict__ stats, int n) {
    __shared__ float ls[4][HF], lq[4][HF];
    int c = threadIdx.x & 63, w = threadIdx.x >> 6;
    float s = 0.f, q = 0.f;
    for (int r = blockIdx.x * 4 + w; r < n; r += gridDim.x * 4) {
        float v = V[(size_t)r * HF + c];
        s += v;
        q += v * v;
    }
    ls[w][c] = s;
    lq[w][c] = q;
    __syncthreads();
    if (w == 0) {
        atomicAdd(&stats[c], ls[0][c] + ls[1][c] + ls[2][c] + ls[3][c]);
        atomicAdd(&stats[HF + c], lq[0][c] + lq[1][c] + lq[2][c] + lq[3][c]);
    }
}

__global__ void k_bnparams(float* __restrict__ stats, const float* __restrict__ g,
                           const float* __restrict__ be, float n) {
    int c = threadIdx.x;  // 64 threads
    float mu = stats[c] / n;
    float var = stats[HF + c] / n - mu * mu;  // biased var
    float a = g[c] * rsqrtf(var + 1e-5f);
    stats[128 + c] = a;
    stats[192 + c] = be[c] - mu * a;
}

// BN+ReLU then LDS transpose: V [n][64] -> XT [64][n]. Grid ceil(n/64).
__global__ __launch_bounds__(256) void k_bnapply_t(const float* __restrict__ V,
                                                   const float* __restrict__ stats,
                                                   float* __restrict__ XT, int n) {
    __shared__ float t[64][65];
    int r0 = blockIdx.x * 64;
    int c = threadIdx.x & 63, rr = threadIdx.x >> 6;
    float sa = stats[128 + c], sb = stats[192 + c];
#pragma unroll
    for (int i = 0; i < 16; ++i) {
        int r = r0 + i * 4 + rr;
        float v = (r < n) ? V[(size_t)r * HF + c] : 0.f;
        t[i * 4 + rr][c] = fmaxf(fmaf(sa, v, sb), 0.f);
    }
    __syncthreads();
    int r = r0 + c;
#pragma unroll
    for (int i = 0; i < 16; ++i) {
        int cc = i * 4 + rr;
        if (r < n) XT[(size_t)cc * n + r] = t[c][cc];
    }
}

// Fallback BN+ReLU, row-major output.
__global__ void k_bnapply(const float* __restrict__ V, const float* __restrict__ stats,
                          float* __restrict__ X, int n) {
    int t = blockIdx.x * 256 + threadIdx.x;
    if (t >= n * HF) return;
    int c = t & 63;
    X[t] = fmaxf(fmaf(stats[128 + c], V[t], stats[192 + c]), 0.0f);
}

// Layer-3 BN+ReLU fused into segmented pool over sorted batch. One block per graph.
__global__ __launch_bounds__(256) void k_pool_seg(const float* __restrict__ V,
                                                  const float* __restrict__ stats,
                                                  const int* __restrict__ batch,
                                                  float* __restrict__ pool, int n) {
    int g = blockIdx.x;
    int a = 0, b = n;
    while (a < b) { int m = (a + b) >> 1; if (batch[m] < g) a = m + 1; else b = m; }
    int lo = a;
    b = n;
    while (a < b) { int m = (a + b) >> 1; if (batch[m] < g + 1) a = m + 1; else b = m; }
    int hi = a;
    int c = threadIdx.x & 63, w = threadIdx.x >> 6;
    float sa = stats[128 + c], sb = stats[192 + c];
    float s = 0.f;
    for (int r = lo + w; r < hi; r += 4)
        s += fmaxf(fmaf(sa, V[(size_t)r * HF + c], sb), 0.f);
    __shared__ float ls[4][HF];
    ls[w][c] = s;
    __syncthreads();
    if (w == 0) pool[g * HF + c] = ls[0][c] + ls[1][c] + ls[2][c] + ls[3][c];
}

__global__ void k_cls(const float* __restrict__ pool, const float* __restrict__ Wc1,
                      const float* __restrict__ bc1, const float* __restrict__ Wc2,
                      const float* __restrict__ bc2, float* __restrict__ out) {
    __shared__ float pl[HF], hr[HF];
    int g = blockIdx.x, c = threadIdx.x;
    pl[c] = pool[g * HF + c];
    __syncthreads();
    float h = bc1[c];
#pragma unroll
    for (int k = 0; k < HF; ++k) h = fmaf(pl[k], Wc1[c * HF + k], h);
    hr[c] = fmaxf(h, 0.f);
    __syncthreads();
    if (c < OUTF) {
        float o = bc2[c];
#pragma unroll
        for (int k = 0; k < HF; ++k) o = fmaf(hr[k], Wc2[c * HF + k], o);
        out[g * OUTF + c] = o;
    }
}

extern "C" void kernel_launch(void* const* d_in, const int* in_sizes, int n_in,
                              void* d_out, int out_size, void* d_ws, size_t ws_size,
                              hipStream_t stream) {
    const float* x = (const float*)d_in[0];
    const int* edge = (const int*)d_in[1];
    const int* batch = (const int*)d_in[2];
    const float* W1 = (const float*)d_in[3];
    const float* b1 = (const float*)d_in[4];
    const float* g1 = (const float*)d_in[5];
    const float* be1 = (const float*)d_in[6];
    const float* W2 = (const float*)d_in[7];
    const float* b2 = (const float*)d_in[8];
    const float* g2 = (const float*)d_in[9];
    const float* be2 = (const float*)d_in[10];
    const float* W3 = (const float*)d_in[11];
    const float* b3 = (const float*)d_in[12];
    const float* g3 = (const float*)d_in[13];
    const float* be3 = (const float*)d_in[14];
    const float* Wc1 = (const float*)d_in[15];
    const float* bc1 = (const float*)d_in[16];
    const float* Wc2 = (const float*)d_in[17];
    const float* bc2 = (const float*)d_in[18];
    float* out = (float*)d_out;

    const int* src = edge;
    const int* dst = edge + NE;

    const size_t N64 = (size_t)NN * HF;
    float* ws = (float*)d_ws;
    float* buf0 = ws;                      // N*64  (Hs)
    float* buf1 = ws + N64;                // N*64  (V)
    float* XT = buf1 + N64;                // N*128 (transposed activations; fat path only)
    const size_t xt_elems = (size_t)NN * INF_;

    // thin layout pieces come after XT in fat mode, directly after buf1 in thin mode
    bool fat;
    {
        size_t fat_elems = 2 * N64 + xt_elems + NN + 256 + (size_t)NG * HF;
        size_t fat_ints = (size_t)NN + (NN + 1) + 128 + NE;
        fat = ws_size >= (fat_elems + fat_ints) * 4 + 1024;
    }
    float* tail = fat ? (XT + xt_elems) : XT;
    float* rdeg = tail;                    // N
    float* stats = rdeg + NN;              // 256
    float* pool = stats + 256;             // NG*64
    int* cnt = (int*)(pool + (size_t)NG * HF);
    int* ro = cnt + NN;                    // N+1
    int* bsum = ro + NN + 1;               // 128
    int* ss = bsum + 128;                  // E

    // ---- CSR build ----
    hipMemsetAsync(cnt, 0, NN * sizeof(int), stream);
    k_hist<<<(NE + 255) / 256, 256, 0, stream>>>(dst, cnt, NE);
    k_rdegi<<<(NN + 255) / 256, 256, 0, stream>>>(cnt, rdeg, NN);
    const int nblk = (NN + 1023) / 1024;
    k_scan1<<<nblk, 256, 0, stream>>>(cnt, ro, bsum, NN);
    k_scan2<<<1, 128, 0, stream>>>(bsum, nblk);
    k_scan3<<<(NN + 255) / 256, 256, 0, stream>>>(ro, cnt, bsum, NN, NE);
    k_scatter<<<(NE + 255) / 256, 256, 0, stream>>>(src, dst, cnt, ss, NE);

    const float* gW[3] = {W1, W2, W3};
    const float* gb[3] = {b1, b2, b3};
    const float* gg[3] = {g1, g2, g3};
    const float* gbe[3] = {be1, be2, be3};

    const int rowblk = (NN + 255) / 256;
    const int tileblk = (NN + 63) / 64;

    if (fat) k_xpose<<<dim3(tileblk, INF_ / 64), 256, 0, stream>>>(x, XT, NN, INF_);

    for (int l = 0; l < 3; ++l) {
        if (fat) {
            if (l == 0)
                k_gemm_t<INF_><<<rowblk, 256, 0, stream>>>(XT, gW[0], gb[0], rdeg, buf0, NN);
            else
                k_gemm_t<HF><<<rowblk, 256, 0, stream>>>(XT, gW[l], gb[l], rdeg, buf0, NN);
        } else {
            if (l == 0)
                k_gemm<INF_><<<rowblk, 256, 0, stream>>>(x, gW[0], gb[0], rdeg, buf0, NN);
            else
                k_gemm<HF><<<rowblk, 256, 0, stream>>>(buf0, gW[l], gb[l], rdeg, buf0, NN);
        }
        k_agg<<<(NN + 3) / 4, 256, 0, stream>>>(ro, ss, buf0, rdeg, buf1, NN);
        hipMemsetAsync(stats, 0, 128 * sizeof(float), stream);
        k_stats<<<1024, 256, 0, stream>>>(buf1, stats, NN);
        k_bnparams<<<1, 64, 0, stream>>>(stats, gg[l], gbe[l], (float)NN);
        if (l < 2) {
            if (fat)
                k_bnapply_t<<<tileblk, 256, 0, stream>>>(buf1, stats, XT, NN);
            else
                k_bnapply<<<((int)N64 + 255) / 256, 256, 0, stream>>>(buf1, stats, buf0, NN);
        } else {
            k_pool_seg<<<NG, 256, 0, stream>>>(buf1, stats, batch, pool, NN);
        }
    }

    k_cls<<<NG, HF, 0, stream>>>(pool, Wc1, bc1, Wc2, bc2, out);
}

// Round 4
// 685.931 us; speedup vs baseline: 1.3921x; 1.3921x over previous
//
#include <hip/hip_runtime.h>
#include <hip/hip_bf16.h>

// GCN graph classifier: 3x (GCNConv -> BN -> ReLU) -> sum-pool -> MLP head.
//   Hs[i] = (relu_bn(x[i])@W.T + b) * rdeg[i]   (LDS-tiled gemm, BN of prev layer fused)
//   V[d]  = rdeg[d]*(Hs[d] + sum_in Hs[s])      (CSR gather, no atomics)
// Pool = segmented sum over sorted batch (binary search bounds, no atomics).

#define NN 100000
#define NE 1600000
#define INF_ 128
#define HF 64
#define OUTF 10
#define NG 128

__global__ void k_hist(const int* __restrict__ dst, int* __restrict__ cnt, int E) {
    int e = blockIdx.x * 256 + threadIdx.x;
    if (e < E) atomicAdd(&cnt[dst[e]], 1);
}

__global__ void k_rdegi(const int* __restrict__ cnt, float* __restrict__ rdeg, int n) {
    int i = blockIdx.x * 256 + threadIdx.x;
    if (i < n) rdeg[i] = rsqrtf((float)cnt[i] + 1.0f);  // +1 = self loop
}

__global__ void k_scan1(const int* __restrict__ cnt, int* __restrict__ ro,
                        int* __restrict__ bsum, int n) {
    __shared__ int ts[256];
    int base = blockIdx.x * 1024 + threadIdx.x * 4;
    int v[4], s = 0;
#pragma unroll
    for (int k = 0; k < 4; ++k) {
        int idx = base + k;
        v[k] = (idx < n) ? cnt[idx] : 0;
        s += v[k];
    }
    ts[threadIdx.x] = s;
    __syncthreads();
    for (int off = 1; off < 256; off <<= 1) {
        int t = (threadIdx.x >= off) ? ts[threadIdx.x - off] : 0;
        __syncthreads();
        ts[threadIdx.x] += t;
        __syncthreads();
    }
    int ex = ts[threadIdx.x] - s;
    if (threadIdx.x == 255) bsum[blockIdx.x] = ts[255];
#pragma unroll
    for (int k = 0; k < 4; ++k) {
        int idx = base + k;
        if (idx < n) ro[idx] = ex;
        ex += v[k];
    }
}

__global__ void k_scan2(int* __restrict__ bsum, int nb) {
    __shared__ int ts[128];
    int i = threadIdx.x;
    int v = (i < nb) ? bsum[i] : 0;
    ts[i] = v;
    __syncthreads();
    for (int off = 1; off < 128; off <<= 1) {
        int t = (i >= off) ? ts[i - off] : 0;
        __syncthreads();
        ts[i] += t;
        __syncthreads();
    }
    if (i < nb) bsum[i] = ts[i] - v;
}

__global__ void k_scan3(int* __restrict__ ro, int* __restrict__ cursor,
                        const int* __restrict__ bsum, int n, int E) {
    int i = blockIdx.x * 256 + threadIdx.x;
    if (i < n) {
        int v = ro[i] + bsum[i >> 10];
        ro[i] = v;
        cursor[i] = v;
    }
    if (i == 0) ro[n] = E;
}

__global__ void k_scatter(const int* __restrict__ src, const int* __restrict__ dst,
                          int* __restrict__ cursor, int* __restrict__ ss, int E) {
    int e = blockIdx.x * 256 + threadIdx.x;
    if (e < E) {
        int pos = atomicAdd(&cursor[dst[e]], 1);
        ss[pos] = src[e];
    }
}

// LDS-tiled GEMM: 64-row tile per block, 256 threads (4 waves).
// Wave w computes channels [16w,16w+16); thread's row = lane. X staged
// transposed in LDS (xs[k][row], pad 65 -> conflict-free). Optional fused
// BN+ReLU of the previous layer on the staged tile. Coalesced f4 in/out.
template<int K, bool BN>
__global__ __launch_bounds__(256) void k_gemm_lds(const float* __restrict__ X,
                                                  const float* __restrict__ W,
                                                  const float* __restrict__ bias,
                                                  const float* __restrict__ rdeg,
                                                  const float* __restrict__ stats,
                                                  float* __restrict__ Hs, int n) {
    __shared__ float lds[64 * 65];  // union: xs[32][65] chunk stage / ys[64][65] out stage
    const int t = threadIdx.x;
    const int lane = t & 63;
    const int o0 = __builtin_amdgcn_readfirstlane((t >> 6) * 16);
    const int r0 = blockIdx.x * 64;
    float acc[16];
#pragma unroll
    for (int o = 0; o < 16; ++o) acc[o] = 0.f;

    for (int kk = 0; kk < K; kk += 32) {
        __syncthreads();  // previous chunk fully consumed
#pragma unroll
        for (int j = 0; j < 2; ++j) {
            int flatq = t + 256 * j;        // 512 float4 = 64 rows x 32 cols
            int r = flatq >> 3;
            int c = (flatq & 7) * 4;
            int row = r0 + r;
            float4 v = make_float4(0.f, 0.f, 0.f, 0.f);
            if (row < n) v = *(const float4*)(X + (size_t)row * K + kk + c);
            if (BN) {
                float4 sa = *(const float4*)(stats + 128 + kk + c);
                float4 sb = *(const float4*)(stats + 192 + kk + c);
                v.x = fmaxf(fmaf(sa.x, v.x, sb.x), 0.f);
                v.y = fmaxf(fmaf(sa.y, v.y, sb.y), 0.f);
                v.z = fmaxf(fmaf(sa.z, v.z, sb.z), 0.f);
                v.w = fmaxf(fmaf(sa.w, v.w, sb.w), 0.f);
            }
            lds[(c + 0) * 65 + r] = v.x;
            lds[(c + 1) * 65 + r] = v.y;
            lds[(c + 2) * 65 + r] = v.z;
            lds[(c + 3) * 65 + r] = v.w;
        }
        __syncthreads();
#pragma unroll
        for (int k = 0; k < 32; ++k) {
            float x = lds[k * 65 + lane];
            const float* wp = W + (size_t)o0 * K + kk + k;
#pragma unroll
            for (int o = 0; o < 16; ++o)
                acc[o] = fmaf(x, wp[(size_t)o * K], acc[o]);
        }
    }

    // epilogue: scale by rdeg, add bias, restage via LDS for coalesced stores
    int myrow = r0 + lane;
    float rv = (myrow < n) ? rdeg[myrow] : 0.f;
    __syncthreads();
#pragma unroll
    for (int o = 0; o < 16; ++o)
        lds[lane * 65 + o0 + o] = (bias[o0 + o] + acc[o]) * rv;
    __syncthreads();
#pragma unroll
    for (int j = 0; j < 4; ++j) {
        int flatq = t + 256 * j;            // 1024 float4 = 64 rows x 64 cols
        int r = flatq >> 4;
        int oq = (flatq & 15) * 4;
        int row = r0 + r;
        if (row < n) {
            float4 v = make_float4(lds[r * 65 + oq], lds[r * 65 + oq + 1],
                                   lds[r * 65 + oq + 2], lds[r * 65 + oq + 3]);
            *(float4*)(Hs + (size_t)row * HF + oq) = v;
        }
    }
}

// One wave per node, lane = channel. V = rdeg*(Hs[self] + sum Hs[src]).
__global__ __launch_bounds__(256) void k_agg(const int* __restrict__ ro,
                                             const int* __restrict__ ss,
                                             const float* __restrict__ Hs,
                                             const float* __restrict__ rdeg,
                                             float* __restrict__ V, int n) {
    int node = blockIdx.x * 4 + (threadIdx.x >> 6);
    if (node >= n) return;
    int lane = threadIdx.x & 63;
    int beg = ro[node], end = ro[node + 1];
    float acc = Hs[(size_t)node * HF + lane];
    int j = beg;
    for (; j + 3 < end; j += 4) {
        int s0 = ss[j], s1 = ss[j + 1], s2 = ss[j + 2], s3 = ss[j + 3];
        float v0 = Hs[(size_t)s0 * HF + lane];
        float v1 = Hs[(size_t)s1 * HF + lane];
        float v2 = Hs[(size_t)s2 * HF + lane];
        float v3 = Hs[(size_t)s3 * HF + lane];
        acc += v0 + v1 + v2 + v3;
    }
    for (; j < end; ++j) acc += Hs[(size_t)ss[j] * HF + lane];
    V[(size_t)node * HF + lane] = rdeg[node] * acc;
}

__global__ void k_stats(const float* __restrict__ V, float* __restrict__ stats, int n) {
    __shared__ float ls[4][HF], lq[4][HF];
    int c = threadIdx.x & 63, w = threadIdx.x >> 6;
    float s = 0.f, q = 0.f;
    for (int r = blockIdx.x * 4 + w; r < n; r += gridDim.x * 4) {
        float v = V[(size_t)r * HF + c];
        s += v;
        q += v * v;
    }
    ls[w][c] = s;
    lq[w][c] = q;
    __syncthreads();
    if (w == 0) {
        atomicAdd(&stats[c], ls[0][c] + ls[1][c] + ls[2][c] + ls[3][c]);
        atomicAdd(&stats[HF + c], lq[0][c] + lq[1][c] + lq[2][c] + lq[3][c]);
    }
}

__global__ void k_bnparams(float* __restrict__ stats, const float* __restrict__ g,
                           const float* __restrict__ be, float n) {
    int c = threadIdx.x;  // 64 threads
    float mu = stats[c] / n;
    float var = stats[HF + c] / n - mu * mu;  // biased var
    float a = g[c] * rsqrtf(var + 1e-5f);
    stats[128 + c] = a;
    stats[192 + c] = be[c] - mu * a;
}

// Layer-3 BN+ReLU fused into segmented pool over sorted batch. One block per graph.
__global__ __launch_bounds__(256) void k_pool_seg(const float* __restrict__ V,
                                                  const float* __restrict__ stats,
                                                  const int* __restrict__ batch,
                                                  float* __restrict__ pool, int n) {
    int g = blockIdx.x;
    int a = 0, b = n;
    while (a < b) { int m = (a + b) >> 1; if (batch[m] < g) a = m + 1; else b = m; }
    int lo = a;
    b = n;
    while (a < b) { int m = (a + b) >> 1; if (batch[m] < g + 1) a = m + 1; else b = m; }
    int hi = a;
    int c = threadIdx.x & 63, w = threadIdx.x >> 6;
    float sa = stats[128 + c], sb = stats[192 + c];
    float s = 0.f;
    for (int r = lo + w; r < hi; r += 4)
        s += fmaxf(fmaf(sa, V[(size_t)r * HF + c], sb), 0.f);
    __shared__ float ls[4][HF];
    ls[w][c] = s;
    __syncthreads();
    if (w == 0) pool[g * HF + c] = ls[0][c] + ls[1][c] + ls[2][c] + ls[3][c];
}

__global__ void k_cls(const float* __restrict__ pool, const float* __restrict__ Wc1,
                      const float* __restrict__ bc1, const float* __restrict__ Wc2,
                      const float* __restrict__ bc2, float* __restrict__ out) {
    __shared__ float pl[HF], hr[HF];
    int g = blockIdx.x, c = threadIdx.x;
    pl[c] = pool[g * HF + c];
    __syncthreads();
    float h = bc1[c];
#pragma unroll
    for (int k = 0; k < HF; ++k) h = fmaf(pl[k], Wc1[c * HF + k], h);
    hr[c] = fmaxf(h, 0.f);
    __syncthreads();
    if (c < OUTF) {
        float o = bc2[c];
#pragma unroll
        for (int k = 0; k < HF; ++k) o = fmaf(hr[k], Wc2[c * HF + k], o);
        out[g * OUTF + c] = o;
    }
}

extern "C" void kernel_launch(void* const* d_in, const int* in_sizes, int n_in,
                              void* d_out, int out_size, void* d_ws, size_t ws_size,
                              hipStream_t stream) {
    const float* x = (const float*)d_in[0];
    const int* edge = (const int*)d_in[1];
    const int* batch = (const int*)d_in[2];
    const float* W1 = (const float*)d_in[3];
    const float* b1 = (const float*)d_in[4];
    const float* g1 = (const float*)d_in[5];
    const float* be1 = (const float*)d_in[6];
    const float* W2 = (const float*)d_in[7];
    const float* b2 = (const float*)d_in[8];
    const float* g2 = (const float*)d_in[9];
    const float* be2 = (const float*)d_in[10];
    const float* W3 = (const float*)d_in[11];
    const float* b3 = (const float*)d_in[12];
    const float* g3 = (const float*)d_in[13];
    const float* be3 = (const float*)d_in[14];
    const float* Wc1 = (const float*)d_in[15];
    const float* bc1 = (const float*)d_in[16];
    const float* Wc2 = (const float*)d_in[17];
    const float* bc2 = (const float*)d_in[18];
    float* out = (float*)d_out;

    const int* src = edge;
    const int* dst = edge + NE;

    const size_t N64 = (size_t)NN * HF;
    float* ws = (float*)d_ws;
    float* buf0 = ws;                      // N*64  (Hs)
    float* buf1 = ws + N64;                // N*64  (V)
    float* rdeg = buf1 + N64;              // N
    float* stats = rdeg + NN;              // 256: sum|sumsq|a|b2
    float* pool = stats + 256;             // NG*64
    int* cnt = (int*)(pool + (size_t)NG * HF);  // N (hist, then cursor)
    int* ro = cnt + NN;                    // N+1
    int* bsum = ro + NN + 1;               // 128
    int* ss = bsum + 128;                  // E

    // ---- CSR build ----
    hipMemsetAsync(cnt, 0, NN * sizeof(int), stream);
    k_hist<<<(NE + 255) / 256, 256, 0, stream>>>(dst, cnt, NE);
    k_rdegi<<<(NN + 255) / 256, 256, 0, stream>>>(cnt, rdeg, NN);
    const int nblk = (NN + 1023) / 1024;
    k_scan1<<<nblk, 256, 0, stream>>>(cnt, ro, bsum, NN);
    k_scan2<<<1, 128, 0, stream>>>(bsum, nblk);
    k_scan3<<<(NN + 255) / 256, 256, 0, stream>>>(ro, cnt, bsum, NN, NE);
    k_scatter<<<(NE + 255) / 256, 256, 0, stream>>>(src, dst, cnt, ss, NE);

    const float* gW[3] = {W1, W2, W3};
    const float* gb[3] = {b1, b2, b3};
    const float* gg[3] = {g1, g2, g3};
    const float* gbe[3] = {be1, be2, be3};

    const int tileblk = (NN + 63) / 64;

    for (int l = 0; l < 3; ++l) {
        if (l == 0)
            k_gemm_lds<INF_, false><<<tileblk, 256, 0, stream>>>(x, gW[0], gb[0], rdeg, stats, buf0, NN);
        else
            k_gemm_lds<HF, true><<<tileblk, 256, 0, stream>>>(buf1, gW[l], gb[l], rdeg, stats, buf0, NN);
        k_agg<<<(NN + 3) / 4, 256, 0, stream>>>(ro, ss, buf0, rdeg, buf1, NN);
        hipMemsetAsync(stats, 0, 128 * sizeof(float), stream);
        k_stats<<<1024, 256, 0, stream>>>(buf1, stats, NN);
        k_bnparams<<<1, 64, 0, stream>>>(stats, gg[l], gbe[l], (float)NN);
        if (l == 2)
            k_pool_seg<<<NG, 256, 0, stream>>>(buf1, stats, batch, pool, NN);
    }

    k_cls<<<NG, HF, 0, stream>>>(pool, Wc1, bc1, Wc2, bc2, out);
}

// Round 5
// 532.537 us; speedup vs baseline: 1.7931x; 1.2880x over previous
//
#include <hip/hip_runtime.h>
#include <hip/hip_bf16.h>

// GCN graph classifier: 3x (GCNConv -> BN -> ReLU) -> sum-pool -> MLP head.
//   Hs[i] = (relu_bn(x[i])@W.T + b) * rdeg[i]   (LDS-tiled gemm, prev-layer BN fused; bf16 out)
//   V[d]  = rdeg[d]*(Hs[d] + sum_in Hs[s])      (CSR gather of bf16 rows, f32 accum)
// CSR built via 2-level bucket sort (no global-atomic scatter, line-dense writes):
//   kA per-block bucket hist -> scan -> kB packed bucket partition -> kC per-bucket
//   node sort emitting ss, ro, rdeg.

#define NN 100000
#define NE 1600000
#define INF_ 128
#define HF 64
#define OUTF 10
#define NG 128
#define NBUCK 196     // ceil(NN/512)
#define NBLKP 128     // partition blocks; NE % NBLKP == 0 -> 12500 edges/block
#define CPB (NE / NBLKP)

static __device__ __forceinline__ unsigned short f2bf(float x) {
    unsigned int b = __float_as_uint(x);
    b += 0x7FFFu + ((b >> 16) & 1u);   // RNE
    return (unsigned short)(b >> 16);
}
static __device__ __forceinline__ float bf2f(unsigned short u) {
    return __uint_as_float(((unsigned int)u) << 16);
}

// ---- CSR build ----
__global__ __launch_bounds__(256) void kA_count(const int* __restrict__ dst,
                                                int* __restrict__ gcount) {
    __shared__ int cnt[256];
    int t = threadIdx.x, blk = blockIdx.x;
    cnt[t] = 0;
    __syncthreads();
    int beg = blk * CPB, end = beg + CPB;
    for (int i = beg + t; i < end; i += 256) atomicAdd(&cnt[dst[i] >> 9], 1);
    __syncthreads();
    if (t < NBUCK) gcount[t * NBLKP + blk] = cnt[t];
}

__global__ void k_scan1(const int* __restrict__ cnt, int* __restrict__ ro,
                        int* __restrict__ bsum, int n) {
    __shared__ int ts[256];
    int base = blockIdx.x * 1024 + threadIdx.x * 4;
    int v[4], s = 0;
#pragma unroll
    for (int k = 0; k < 4; ++k) {
        int idx = base + k;
        v[k] = (idx < n) ? cnt[idx] : 0;
        s += v[k];
    }
    ts[threadIdx.x] = s;
    __syncthreads();
    for (int off = 1; off < 256; off <<= 1) {
        int t = (threadIdx.x >= off) ? ts[threadIdx.x - off] : 0;
        __syncthreads();
        ts[threadIdx.x] += t;
        __syncthreads();
    }
    int ex = ts[threadIdx.x] - s;
    if (threadIdx.x == 255) bsum[blockIdx.x] = ts[255];
#pragma unroll
    for (int k = 0; k < 4; ++k) {
        int idx = base + k;
        if (idx < n) ro[idx] = ex;
        ex += v[k];
    }
}

__global__ void k_scan2(int* __restrict__ bsum, int nb) {
    __shared__ int ts[128];
    int i = threadIdx.x;
    int v = (i < nb) ? bsum[i] : 0;
    ts[i] = v;
    __syncthreads();
    for (int off = 1; off < 128; off <<= 1) {
        int t = (i >= off) ? ts[i - off] : 0;
        __syncthreads();
        ts[i] += t;
        __syncthreads();
    }
    if (i < nb) bsum[i] = ts[i] - v;
}

__global__ void k_scan3g(int* __restrict__ goff, const int* __restrict__ bsum, int n) {
    int i = blockIdx.x * 256 + threadIdx.x;
    if (i < n) goff[i] += bsum[i >> 10];
}

// Partition edges into bucket-major, block-private runs. tmp = (dst&511)<<17 | src.
__global__ __launch_bounds__(256) void kB_part(const int* __restrict__ src,
                                               const int* __restrict__ dst,
                                               const int* __restrict__ goff,
                                               int* __restrict__ tmp) {
    __shared__ int cur[NBUCK];
    int t = threadIdx.x, blk = blockIdx.x;
    if (t < NBUCK) cur[t] = goff[t * NBLKP + blk];
    __syncthreads();
    int beg = blk * CPB, end = beg + CPB;
    for (int i = beg + t; i < end; i += 256) {
        int d = dst[i];
        int pos = atomicAdd(&cur[d >> 9], 1);
        tmp[pos] = ((d & 511) << 17) | src[i];
    }
}

// One block per bucket: per-node hist+scan -> ro, rdeg, node-sorted ss.
__global__ __launch_bounds__(256) void kC_build(const int* __restrict__ goff,
                                                int* __restrict__ tmp,
                                                int* __restrict__ ss,
                                                int* __restrict__ ro,
                                                float* __restrict__ rdeg, int E) {
    __shared__ int cnt[512];
    __shared__ int ts[256];
    __shared__ int cur[512];
    int t = threadIdx.x, b = blockIdx.x;
    int beg = goff[b * NBLKP];
    int end = (b + 1 < NBUCK) ? goff[(b + 1) * NBLKP] : E;
    cnt[t] = 0;
    cnt[t + 256] = 0;
    __syncthreads();
    for (int i = beg + t; i < end; i += 256) atomicAdd(&cnt[tmp[i] >> 17], 1);
    __syncthreads();
    int a0 = cnt[2 * t], a1 = cnt[2 * t + 1], s = a0 + a1;
    ts[t] = s;
    __syncthreads();
    for (int off = 1; off < 256; off <<= 1) {
        int v = (t >= off) ? ts[t - off] : 0;
        __syncthreads();
        ts[t] += v;
        __syncthreads();
    }
    int ex = ts[t] - s;
    int p0 = beg + ex, p1 = beg + ex + a0;
    cur[2 * t] = p0;
    cur[2 * t + 1] = p1;
    int node0 = (b << 9) + 2 * t;
    if (node0 < NN) { ro[node0] = p0; rdeg[node0] = rsqrtf((float)a0 + 1.f); }
    else if (node0 == NN) ro[NN] = p0;
    int node1 = node0 + 1;
    if (node1 < NN) { ro[node1] = p1; rdeg[node1] = rsqrtf((float)a1 + 1.f); }
    else if (node1 == NN) ro[NN] = p1;
    __syncthreads();
    for (int i = beg + t; i < end; i += 256) {
        int p = tmp[i];
        int pos = atomicAdd(&cur[p >> 17], 1);
        ss[pos] = p & 0x1FFFF;
    }
}

// ---- LDS-tiled GEMM: 64-row tile, 256 threads; wave w -> channels [16w,16w+16).
// BN=true: apply relu(sa*v+sb) of PREVIOUS layer to staged input (params computed
// in-kernel from raw sums). Output Hs in bf16.
template<int K, bool BN>
__global__ __launch_bounds__(256) void k_gemm_lds(const float* __restrict__ X,
                                                  const float* __restrict__ W,
                                                  const float* __restrict__ bias,
                                                  const float* __restrict__ rdeg,
                                                  const float* __restrict__ stats,
                                                  const float* __restrict__ g,
                                                  const float* __restrict__ be,
                                                  unsigned short* __restrict__ Hs, int n) {
    __shared__ float lds[64 * 65];
    __shared__ float sa_l[64], sb_l[64];
    const int t = threadIdx.x;
    const int lane = t & 63;
    const int o0 = __builtin_amdgcn_readfirstlane((t >> 6) * 16);
    const int r0 = blockIdx.x * 64;
    if (BN && t < 64) {
        float n_ = (float)NN;
        float mu = stats[t] / n_;
        float var = stats[64 + t] / n_ - mu * mu;
        float a = g[t] * rsqrtf(var + 1e-5f);
        sa_l[t] = a;
        sb_l[t] = be[t] - mu * a;
    }
    float acc[16];
#pragma unroll
    for (int o = 0; o < 16; ++o) acc[o] = 0.f;

    for (int kk = 0; kk < K; kk += 32) {
        __syncthreads();
#pragma unroll
        for (int j = 0; j < 2; ++j) {
            int flatq = t + 256 * j;
            int r = flatq >> 3;
            int c = (flatq & 7) * 4;
            int row = r0 + r;
            float4 v = make_float4(0.f, 0.f, 0.f, 0.f);
            if (row < n) v = *(const float4*)(X + (size_t)row * K + kk + c);
            if (BN) {
                v.x = fmaxf(fmaf(sa_l[kk + c + 0], v.x, sb_l[kk + c + 0]), 0.f);
                v.y = fmaxf(fmaf(sa_l[kk + c + 1], v.y, sb_l[kk + c + 1]), 0.f);
                v.z = fmaxf(fmaf(sa_l[kk + c + 2], v.z, sb_l[kk + c + 2]), 0.f);
                v.w = fmaxf(fmaf(sa_l[kk + c + 3], v.w, sb_l[kk + c + 3]), 0.f);
            }
            lds[(c + 0) * 65 + r] = v.x;
            lds[(c + 1) * 65 + r] = v.y;
            lds[(c + 2) * 65 + r] = v.z;
            lds[(c + 3) * 65 + r] = v.w;
        }
        __syncthreads();
#pragma unroll
        for (int k = 0; k < 32; ++k) {
            float x = lds[k * 65 + lane];
            const float* wp = W + (size_t)o0 * K + kk + k;
#pragma unroll
            for (int o = 0; o < 16; ++o)
                acc[o] = fmaf(x, wp[(size_t)o * K], acc[o]);
        }
    }

    int myrow = r0 + lane;
    float rv = (myrow < n) ? rdeg[myrow] : 0.f;
    __syncthreads();
#pragma unroll
    for (int o = 0; o < 16; ++o)
        lds[lane * 65 + o0 + o] = (bias[o0 + o] + acc[o]) * rv;
    __syncthreads();
    // pack 16 ch per thread -> 2 x uint4 stores, coalesced
    {
        int r = t >> 2;
        int c0 = (t & 3) * 16;
        int row = r0 + r;
        if (row < n) {
            unsigned int u[8];
#pragma unroll
            for (int j = 0; j < 8; ++j) {
                unsigned int lo = f2bf(lds[r * 65 + c0 + 2 * j]);
                unsigned int hi = f2bf(lds[r * 65 + c0 + 2 * j + 1]);
                u[j] = lo | (hi << 16);
            }
            uint4* p = (uint4*)(Hs + (size_t)row * HF + c0);
            p[0] = make_uint4(u[0], u[1], u[2], u[3]);
            p[1] = make_uint4(u[4], u[5], u[6], u[7]);
        }
    }
}

// One wave per node, lane = channel. bf16 gathers, f32 accum.
__global__ __launch_bounds__(256) void k_agg(const int* __restrict__ ro,
                                             const int* __restrict__ ss,
                                             const unsigned short* __restrict__ Hs,
                                             const float* __restrict__ rdeg,
                                             float* __restrict__ V, int n) {
    int node = blockIdx.x * 4 + (threadIdx.x >> 6);
    if (node >= n) return;
    int lane = threadIdx.x & 63;
    int beg = ro[node], end = ro[node + 1];
    float acc = bf2f(Hs[(size_t)node * HF + lane]);
    int j = beg;
    for (; j + 3 < end; j += 4) {
        int s0 = ss[j], s1 = ss[j + 1], s2 = ss[j + 2], s3 = ss[j + 3];
        float v0 = bf2f(Hs[(size_t)s0 * HF + lane]);
        float v1 = bf2f(Hs[(size_t)s1 * HF + lane]);
        float v2 = bf2f(Hs[(size_t)s2 * HF + lane]);
        float v3 = bf2f(Hs[(size_t)s3 * HF + lane]);
        acc += v0 + v1 + v2 + v3;
    }
    for (; j < end; ++j) acc += bf2f(Hs[(size_t)ss[j] * HF + lane]);
    V[(size_t)node * HF + lane] = rdeg[node] * acc;
}

__global__ void k_stats(const float* __restrict__ V, float* __restrict__ stats, int n) {
    __shared__ float ls[4][HF], lq[4][HF];
    int c = threadIdx.x & 63, w = threadIdx.x >> 6;
    float s = 0.f, q = 0.f;
    for (int r = blockIdx.x * 4 + w; r < n; r += gridDim.x * 4) {
        float v = V[(size_t)r * HF + c];
        s += v;
        q += v * v;
    }
    ls[w][c] = s;
    lq[w][c] = q;
    __syncthreads();
    if (w == 0) {
        atomicAdd(&stats[c], ls[0][c] + ls[1][c] + ls[2][c] + ls[3][c]);
        atomicAdd(&stats[HF + c], lq[0][c] + lq[1][c] + lq[2][c] + lq[3][c]);
    }
}

// Layer-3 BN+ReLU fused into segmented pool over sorted batch. One block per graph.
__global__ __launch_bounds__(256) void k_pool_seg(const float* __restrict__ V,
                                                  const float* __restrict__ stats,
                                                  const float* __restrict__ g,
                                                  const float* __restrict__ be,
                                                  const int* __restrict__ batch,
                                                  float* __restrict__ pool, int n) {
    __shared__ float sa_l[64], sb_l[64];
    int t = threadIdx.x;
    if (t < 64) {
        float n_ = (float)NN;
        float mu = stats[t] / n_;
        float var = stats[64 + t] / n_ - mu * mu;
        float a = g[t] * rsqrtf(var + 1e-5f);
        sa_l[t] = a;
        sb_l[t] = be[t] - mu * a;
    }
    __syncthreads();
    int gph = blockIdx.x;
    int a = 0, b = n;
    while (a < b) { int m = (a + b) >> 1; if (batch[m] < gph) a = m + 1; else b = m; }
    int lo = a;
    b = n;
    while (a < b) { int m = (a + b) >> 1; if (batch[m] < gph + 1) a = m + 1; else b = m; }
    int hi = a;
    int c = t & 63, w = t >> 6;
    float sa = sa_l[c], sb = sb_l[c];
    float s = 0.f;
    for (int r = lo + w; r < hi; r += 4)
        s += fmaxf(fmaf(sa, V[(size_t)r * HF + c], sb), 0.f);
    __shared__ float ls[4][HF];
    ls[w][c] = s;
    __syncthreads();
    if (w == 0) pool[gph * HF + c] = ls[0][c] + ls[1][c] + ls[2][c] + ls[3][c];
}

__global__ void k_cls(const float* __restrict__ pool, const float* __restrict__ Wc1,
                      const float* __restrict__ bc1, const float* __restrict__ Wc2,
                      const float* __restrict__ bc2, float* __restrict__ out) {
    __shared__ float pl[HF], hr[HF];
    int g = blockIdx.x, c = threadIdx.x;
    pl[c] = pool[g * HF + c];
    __syncthreads();
    float h = bc1[c];
#pragma unroll
    for (int k = 0; k < HF; ++k) h = fmaf(pl[k], Wc1[c * HF + k], h);
    hr[c] = fmaxf(h, 0.f);
    __syncthreads();
    if (c < OUTF) {
        float o = bc2[c];
#pragma unroll
        for (int k = 0; k < HF; ++k) o = fmaf(hr[k], Wc2[c * HF + k], o);
        out[g * OUTF + c] = o;
    }
}

extern "C" void kernel_launch(void* const* d_in, const int* in_sizes, int n_in,
                              void* d_out, int out_size, void* d_ws, size_t ws_size,
                              hipStream_t stream) {
    const float* x = (const float*)d_in[0];
    const int* edge = (const int*)d_in[1];
    const int* batch = (const int*)d_in[2];
    const float* W1 = (const float*)d_in[3];
    const float* b1 = (const float*)d_in[4];
    const float* g1 = (const float*)d_in[5];
    const float* be1 = (const float*)d_in[6];
    const float* W2 = (const float*)d_in[7];
    const float* b2 = (const float*)d_in[8];
    const float* g2 = (const float*)d_in[9];
    const float* be2 = (const float*)d_in[10];
    const float* W3 = (const float*)d_in[11];
    const float* b3 = (const float*)d_in[12];
    const float* g3 = (const float*)d_in[13];
    const float* be3 = (const float*)d_in[14];
    const float* Wc1 = (const float*)d_in[15];
    const float* bc1 = (const float*)d_in[16];
    const float* Wc2 = (const float*)d_in[17];
    const float* bc2 = (const float*)d_in[18];
    float* out = (float*)d_out;

    const int* src = edge;
    const int* dst = edge + NE;

    const size_t N64 = (size_t)NN * HF;
    float* ws = (float*)d_ws;
    float* V = ws;                                   // N*64 f32
    float* rdeg = V + N64;                           // N
    float* stats = rdeg + NN;                        // 128 (sum | sumsq)
    float* pool = stats + 128;                       // NG*64
    unsigned short* Hs = (unsigned short*)(pool + (size_t)NG * HF);  // N*64 bf16
    int* gcount = (int*)(Hs + N64);                  // NBUCK*NBLKP
    int* goff = gcount + NBUCK * NBLKP;              // NBUCK*NBLKP
    int* bsum = goff + NBUCK * NBLKP;                // 128
    int* ro = bsum + 128;                            // N+1
    int* tmp = ro + NN + 1;                          // E
    int* ss = tmp + NE;                              // E

    // ---- CSR build (2-level bucket sort) ----
    const int NGC = NBUCK * NBLKP;                   // 25088
    kA_count<<<NBLKP, 256, 0, stream>>>(dst, gcount);
    const int nblk = (NGC + 1023) / 1024;            // 25
    k_scan1<<<nblk, 256, 0, stream>>>(gcount, goff, bsum, NGC);
    k_scan2<<<1, 128, 0, stream>>>(bsum, nblk);
    k_scan3g<<<(NGC + 255) / 256, 256, 0, stream>>>(goff, bsum, NGC);
    kB_part<<<NBLKP, 256, 0, stream>>>(src, dst, goff, tmp);
    kC_build<<<NBUCK, 256, 0, stream>>>(goff, tmp, ss, ro, rdeg, NE);

    const float* gW[3] = {W1, W2, W3};
    const float* gb[3] = {b1, b2, b3};
    const float* gg[3] = {g1, g2, g3};
    const float* gbe[3] = {be1, be2, be3};

    const int tileblk = (NN + 63) / 64;

    for (int l = 0; l < 3; ++l) {
        if (l == 0)
            k_gemm_lds<INF_, false><<<tileblk, 256, 0, stream>>>(x, gW[0], gb[0], rdeg,
                                                                 stats, gg[0], gbe[0], Hs, NN);
        else
            k_gemm_lds<HF, true><<<tileblk, 256, 0, stream>>>(V, gW[l], gb[l], rdeg,
                                                              stats, gg[l - 1], gbe[l - 1], Hs, NN);
        k_agg<<<(NN + 3) / 4, 256, 0, stream>>>(ro, ss, Hs, rdeg, V, NN);
        hipMemsetAsync(stats, 0, 128 * sizeof(float), stream);
        k_stats<<<1024, 256, 0, stream>>>(V, stats, NN);
        if (l == 2)
            k_pool_seg<<<NG, 256, 0, stream>>>(V, stats, gg[2], gbe[2], batch, pool, NN);
    }

    k_cls<<<NG, HF, 0, stream>>>(pool, Wc1, bc1, Wc2, bc2, out);
}

// Round 6
// 460.230 us; speedup vs baseline: 2.0748x; 1.1571x over previous
//
#include <hip/hip_runtime.h>
#include <hip/hip_bf16.h>

// GCN graph classifier: 3x (GCNConv -> BN -> ReLU) -> sum-pool -> MLP head.
//   Hs[i] = (relu_bn(x[i])@W.T + b) * rdeg[i]   (LDS-tiled gemm, prev-layer BN fused; bf16 out)
//   V[d]  = rdeg[d]*(Hs[d] + sum_in Hs[s])      (CSR gather; 4ch/lane, 4 nodes/wave; bf16 out)
// CSR via 2-level bucket sort (line-dense writes, LDS atomics only).
// Pool = run-flush segmented sum over sorted batch (wave per 64 rows).

#define NN 100000
#define NE 1600000
#define INF_ 128
#define HF 64
#define OUTF 10
#define NG 128
#define NBUCK 196     // ceil(NN/512)
#define NBLKP 128     // partition blocks; NE % NBLKP == 0 -> 12500 edges/block
#define CPB (NE / NBLKP)

static __device__ __forceinline__ unsigned short f2bf(float x) {
    unsigned int b = __float_as_uint(x);
    b += 0x7FFFu + ((b >> 16) & 1u);   // RNE
    return (unsigned short)(b >> 16);
}
static __device__ __forceinline__ float bf2f(unsigned short u) {
    return __uint_as_float(((unsigned int)u) << 16);
}
static __device__ __forceinline__ float bflo(unsigned int u) {
    return __uint_as_float(u << 16);
}
static __device__ __forceinline__ float bfhi(unsigned int u) {
    return __uint_as_float(u & 0xffff0000u);
}

// ---- CSR build ----
__global__ __launch_bounds__(256) void kA_count(const int* __restrict__ dst,
                                                int* __restrict__ gcount) {
    __shared__ int cnt[256];
    int t = threadIdx.x, blk = blockIdx.x;
    cnt[t] = 0;
    __syncthreads();
    int beg = blk * CPB, end = beg + CPB;
    for (int i = beg + t; i < end; i += 256) atomicAdd(&cnt[dst[i] >> 9], 1);
    __syncthreads();
    if (t < NBUCK) gcount[t * NBLKP + blk] = cnt[t];
}

__global__ void k_scan1(const int* __restrict__ cnt, int* __restrict__ ro,
                        int* __restrict__ bsum, int n) {
    __shared__ int ts[256];
    int base = blockIdx.x * 1024 + threadIdx.x * 4;
    int v[4], s = 0;
#pragma unroll
    for (int k = 0; k < 4; ++k) {
        int idx = base + k;
        v[k] = (idx < n) ? cnt[idx] : 0;
        s += v[k];
    }
    ts[threadIdx.x] = s;
    __syncthreads();
    for (int off = 1; off < 256; off <<= 1) {
        int t = (threadIdx.x >= off) ? ts[threadIdx.x - off] : 0;
        __syncthreads();
        ts[threadIdx.x] += t;
        __syncthreads();
    }
    int ex = ts[threadIdx.x] - s;
    if (threadIdx.x == 255) bsum[blockIdx.x] = ts[255];
#pragma unroll
    for (int k = 0; k < 4; ++k) {
        int idx = base + k;
        if (idx < n) ro[idx] = ex;
        ex += v[k];
    }
}

__global__ void k_scan2(int* __restrict__ bsum, int nb) {
    __shared__ int ts[128];
    int i = threadIdx.x;
    int v = (i < nb) ? bsum[i] : 0;
    ts[i] = v;
    __syncthreads();
    for (int off = 1; off < 128; off <<= 1) {
        int t = (i >= off) ? ts[i - off] : 0;
        __syncthreads();
        ts[i] += t;
        __syncthreads();
    }
    if (i < nb) bsum[i] = ts[i] - v;
}

__global__ void k_scan3g(int* __restrict__ goff, const int* __restrict__ bsum, int n) {
    int i = blockIdx.x * 256 + threadIdx.x;
    if (i < n) goff[i] += bsum[i >> 10];
}

__global__ __launch_bounds__(256) void kB_part(const int* __restrict__ src,
                                               const int* __restrict__ dst,
                                               const int* __restrict__ goff,
                                               int* __restrict__ tmp) {
    __shared__ int cur[NBUCK];
    int t = threadIdx.x, blk = blockIdx.x;
    if (t < NBUCK) cur[t] = goff[t * NBLKP + blk];
    __syncthreads();
    int beg = blk * CPB, end = beg + CPB;
    for (int i = beg + t; i < end; i += 256) {
        int d = dst[i];
        int pos = atomicAdd(&cur[d >> 9], 1);
        tmp[pos] = ((d & 511) << 17) | src[i];
    }
}

__global__ __launch_bounds__(256) void kC_build(const int* __restrict__ goff,
                                                int* __restrict__ tmp,
                                                int* __restrict__ ss,
                                                int* __restrict__ ro,
                                                float* __restrict__ rdeg, int E) {
    __shared__ int cnt[512];
    __shared__ int ts[256];
    __shared__ int cur[512];
    int t = threadIdx.x, b = blockIdx.x;
    int beg = goff[b * NBLKP];
    int end = (b + 1 < NBUCK) ? goff[(b + 1) * NBLKP] : E;
    cnt[t] = 0;
    cnt[t + 256] = 0;
    __syncthreads();
    for (int i = beg + t; i < end; i += 256) atomicAdd(&cnt[tmp[i] >> 17], 1);
    __syncthreads();
    int a0 = cnt[2 * t], a1 = cnt[2 * t + 1], s = a0 + a1;
    ts[t] = s;
    __syncthreads();
    for (int off = 1; off < 256; off <<= 1) {
        int v = (t >= off) ? ts[t - off] : 0;
        __syncthreads();
        ts[t] += v;
        __syncthreads();
    }
    int ex = ts[t] - s;
    int p0 = beg + ex, p1 = beg + ex + a0;
    cur[2 * t] = p0;
    cur[2 * t + 1] = p1;
    int node0 = (b << 9) + 2 * t;
    if (node0 < NN) { ro[node0] = p0; rdeg[node0] = rsqrtf((float)a0 + 1.f); }
    else if (node0 == NN) ro[NN] = p0;
    int node1 = node0 + 1;
    if (node1 < NN) { ro[node1] = p1; rdeg[node1] = rsqrtf((float)a1 + 1.f); }
    else if (node1 == NN) ro[NN] = p1;
    __syncthreads();
    for (int i = beg + t; i < end; i += 256) {
        int p = tmp[i];
        int pos = atomicAdd(&cur[p >> 17], 1);
        ss[pos] = p & 0x1FFFF;
    }
}

// ---- LDS-tiled GEMM: 64-row tile, 256 threads; wave w -> channels [16w,16w+16).
// BN=true: input is bf16 V, apply relu(sa*v+sb) (params from raw sums) while staging.
// BN=false: input is f32 x. Output Hs bf16.
template<int K, bool BN>
__global__ __launch_bounds__(256) void k_gemm_lds(const float* __restrict__ Xf,
                                                  const unsigned short* __restrict__ Xh,
                                                  const float* __restrict__ W,
                                                  const float* __restrict__ bias,
                                                  const float* __restrict__ rdeg,
                                                  const float* __restrict__ stats,
                                                  const float* __restrict__ g,
                                                  const float* __restrict__ be,
                                                  unsigned short* __restrict__ Hs, int n) {
    __shared__ float lds[64 * 65];
    __shared__ float sa_l[64], sb_l[64];
    const int t = threadIdx.x;
    const int lane = t & 63;
    const int o0 = __builtin_amdgcn_readfirstlane((t >> 6) * 16);
    const int r0 = blockIdx.x * 64;
    if (BN && t < 64) {
        float n_ = (float)NN;
        float mu = stats[t] / n_;
        float var = stats[64 + t] / n_ - mu * mu;
        float a = g[t] * rsqrtf(var + 1e-5f);
        sa_l[t] = a;
        sb_l[t] = be[t] - mu * a;
    }
    float acc[16];
#pragma unroll
    for (int o = 0; o < 16; ++o) acc[o] = 0.f;

    for (int kk = 0; kk < K; kk += 32) {
        __syncthreads();
#pragma unroll
        for (int j = 0; j < 2; ++j) {
            int flatq = t + 256 * j;
            int r = flatq >> 3;
            int c = (flatq & 7) * 4;
            int row = r0 + r;
            float4 v = make_float4(0.f, 0.f, 0.f, 0.f);
            if (BN) {
                uint2 u = make_uint2(0u, 0u);
                if (row < n) u = *(const uint2*)(Xh + (size_t)row * K + kk + c);
                v.x = bflo(u.x); v.y = bfhi(u.x); v.z = bflo(u.y); v.w = bfhi(u.y);
                v.x = fmaxf(fmaf(sa_l[kk + c + 0], v.x, sb_l[kk + c + 0]), 0.f);
                v.y = fmaxf(fmaf(sa_l[kk + c + 1], v.y, sb_l[kk + c + 1]), 0.f);
                v.z = fmaxf(fmaf(sa_l[kk + c + 2], v.z, sb_l[kk + c + 2]), 0.f);
                v.w = fmaxf(fmaf(sa_l[kk + c + 3], v.w, sb_l[kk + c + 3]), 0.f);
            } else {
                if (row < n) v = *(const float4*)(Xf + (size_t)row * K + kk + c);
            }
            lds[(c + 0) * 65 + r] = v.x;
            lds[(c + 1) * 65 + r] = v.y;
            lds[(c + 2) * 65 + r] = v.z;
            lds[(c + 3) * 65 + r] = v.w;
        }
        __syncthreads();
#pragma unroll
        for (int k = 0; k < 32; ++k) {
            float x = lds[k * 65 + lane];
            const float* wp = W + (size_t)o0 * K + kk + k;
#pragma unroll
            for (int o = 0; o < 16; ++o)
                acc[o] = fmaf(x, wp[(size_t)o * K], acc[o]);
        }
    }

    int myrow = r0 + lane;
    float rv = (myrow < n) ? rdeg[myrow] : 0.f;
    __syncthreads();
#pragma unroll
    for (int o = 0; o < 16; ++o)
        lds[lane * 65 + o0 + o] = (bias[o0 + o] + acc[o]) * rv;
    __syncthreads();
    {
        int r = t >> 2;
        int c0 = (t & 3) * 16;
        int row = r0 + r;
        if (row < n) {
            unsigned int u[8];
#pragma unroll
            for (int j = 0; j < 8; ++j) {
                unsigned int lo = f2bf(lds[r * 65 + c0 + 2 * j]);
                unsigned int hi = f2bf(lds[r * 65 + c0 + 2 * j + 1]);
                u[j] = lo | (hi << 16);
            }
            uint4* p = (uint4*)(Hs + (size_t)row * HF + c0);
            p[0] = make_uint4(u[0], u[1], u[2], u[3]);
            p[1] = make_uint4(u[4], u[5], u[6], u[7]);
        }
    }
}

// Aggregation: quarter-wave per node (16 lanes x 4 ch via uint2), 4 nodes/wave.
// V16 = bf16( rdeg*(Hs[self] + sum Hs[src]) ).
__global__ __launch_bounds__(256) void k_agg(const int* __restrict__ ro,
                                             const int* __restrict__ ss,
                                             const unsigned short* __restrict__ Hs,
                                             const float* __restrict__ rdeg,
                                             unsigned short* __restrict__ V16, int n) {
    int wid = blockIdx.x * 4 + (threadIdx.x >> 6);
    int sub = (threadIdx.x >> 4) & 3;
    int c4 = (threadIdx.x & 15) * 4;
    int node = wid * 4 + sub;
    bool vn = node < n;
    int beg = 0, d = 0;
    if (vn) {
        beg = ro[node];
        d = ro[node + 1] - beg;
    }
    float4 acc = make_float4(0.f, 0.f, 0.f, 0.f);
    if (vn) {
        uint2 u = *(const uint2*)(Hs + ((size_t)node << 6) + c4);
        acc.x = bflo(u.x); acc.y = bfhi(u.x); acc.z = bflo(u.y); acc.w = bfhi(u.y);
    }
    int dm = d;
    dm = max(dm, __shfl_xor(dm, 16));
    dm = max(dm, __shfl_xor(dm, 32));
    int it = 0;
    for (; it + 1 < dm; it += 2) {
        bool a0 = it < d, a1 = it + 1 < d;
        int s0 = 0, s1 = 0;
        if (a0) s0 = ss[beg + it];
        if (a1) s1 = ss[beg + it + 1];
        uint2 u0 = make_uint2(0u, 0u), u1 = make_uint2(0u, 0u);
        if (a0) u0 = *(const uint2*)(Hs + ((size_t)s0 << 6) + c4);
        if (a1) u1 = *(const uint2*)(Hs + ((size_t)s1 << 6) + c4);
        acc.x += bflo(u0.x) + bflo(u1.x);
        acc.y += bfhi(u0.x) + bfhi(u1.x);
        acc.z += bflo(u0.y) + bflo(u1.y);
        acc.w += bfhi(u0.y) + bfhi(u1.y);
    }
    if (it < dm) {
        bool a0 = it < d;
        int s0 = 0;
        if (a0) s0 = ss[beg + it];
        uint2 u0 = make_uint2(0u, 0u);
        if (a0) u0 = *(const uint2*)(Hs + ((size_t)s0 << 6) + c4);
        acc.x += bflo(u0.x);
        acc.y += bfhi(u0.x);
        acc.z += bflo(u0.y);
        acc.w += bfhi(u0.y);
    }
    if (vn) {
        float rv = rdeg[node];
        unsigned int p0 = (unsigned int)f2bf(acc.x * rv) | ((unsigned int)f2bf(acc.y * rv) << 16);
        unsigned int p1 = (unsigned int)f2bf(acc.z * rv) | ((unsigned int)f2bf(acc.w * rv) << 16);
        *(uint2*)(V16 + ((size_t)node << 6) + c4) = make_uint2(p0, p1);
    }
}

__global__ void k_stats(const unsigned short* __restrict__ V16,
                        float* __restrict__ stats, int n) {
    __shared__ float ls[4][HF], lq[4][HF];
    int c = threadIdx.x & 63, w = threadIdx.x >> 6;
    float s = 0.f, q = 0.f;
    for (int r = blockIdx.x * 4 + w; r < n; r += gridDim.x * 4) {
        float v = bf2f(V16[(size_t)r * HF + c]);
        s += v;
        q += v * v;
    }
    ls[w][c] = s;
    lq[w][c] = q;
    __syncthreads();
    if (w == 0) {
        atomicAdd(&stats[c], ls[0][c] + ls[1][c] + ls[2][c] + ls[3][c]);
        atomicAdd(&stats[HF + c], lq[0][c] + lq[1][c] + lq[2][c] + lq[3][c]);
    }
}

// Pool: wave per 64 consecutive rows, run-flush atomics at graph boundaries.
__global__ __launch_bounds__(256) void k_pool2(const unsigned short* __restrict__ V16,
                                               const float* __restrict__ stats,
                                               const float* __restrict__ g,
                                               const float* __restrict__ be,
                                               const int* __restrict__ batch,
                                               float* __restrict__ pool, int n) {
    __shared__ float sa_l[64], sb_l[64];
    int t = threadIdx.x;
    if (t < 64) {
        float n_ = (float)NN;
        float mu = stats[t] / n_;
        float var = stats[64 + t] / n_ - mu * mu;
        float a = g[t] * rsqrtf(var + 1e-5f);
        sa_l[t] = a;
        sb_l[t] = be[t] - mu * a;
    }
    __syncthreads();
    int wid = blockIdx.x * 4 + (t >> 6);
    int r0 = wid * 64;
    if (r0 >= n) return;
    int lane = t & 63;
    float sa = sa_l[lane], sb = sb_l[lane];
    int rend = min(r0 + 64, n);
    int cur = batch[r0];
    float s = 0.f;
    for (int r = r0; r < rend; ++r) {
        int b = batch[r];
        if (b != cur) {
            atomicAdd(&pool[(size_t)cur * HF + lane], s);
            s = 0.f;
            cur = b;
        }
        float v = bf2f(V16[(size_t)r * HF + lane]);
        s += fmaxf(fmaf(sa, v, sb), 0.f);
    }
    atomicAdd(&pool[(size_t)cur * HF + lane], s);
}

__global__ void k_cls(const float* __restrict__ pool, const float* __restrict__ Wc1,
                      const float* __restrict__ bc1, const float* __restrict__ Wc2,
                      const float* __restrict__ bc2, float* __restrict__ out) {
    __shared__ float pl[HF], hr[HF];
    int g = blockIdx.x, c = threadIdx.x;
    pl[c] = pool[g * HF + c];
    __syncthreads();
    float h = bc1[c];
#pragma unroll
    for (int k = 0; k < HF; ++k) h = fmaf(pl[k], Wc1[c * HF + k], h);
    hr[c] = fmaxf(h, 0.f);
    __syncthreads();
    if (c < OUTF) {
        float o = bc2[c];
#pragma unroll
        for (int k = 0; k < HF; ++k) o = fmaf(hr[k], Wc2[c * HF + k], o);
        out[g * OUTF + c] = o;
    }
}

extern "C" void kernel_launch(void* const* d_in, const int* in_sizes, int n_in,
                              void* d_out, int out_size, void* d_ws, size_t ws_size,
                              hipStream_t stream) {
    const float* x = (const float*)d_in[0];
    const int* edge = (const int*)d_in[1];
    const int* batch = (const int*)d_in[2];
    const float* W1 = (const float*)d_in[3];
    const float* b1 = (const float*)d_in[4];
    const float* g1 = (const float*)d_in[5];
    const float* be1 = (const float*)d_in[6];
    const float* W2 = (const float*)d_in[7];
    const float* b2 = (const float*)d_in[8];
    const float* g2 = (const float*)d_in[9];
    const float* be2 = (const float*)d_in[10];
    const float* W3 = (const float*)d_in[11];
    const float* b3 = (const float*)d_in[12];
    const float* g3 = (const float*)d_in[13];
    const float* be3 = (const float*)d_in[14];
    const float* Wc1 = (const float*)d_in[15];
    const float* bc1 = (const float*)d_in[16];
    const float* Wc2 = (const float*)d_in[17];
    const float* bc2 = (const float*)d_in[18];
    float* out = (float*)d_out;

    const int* src = edge;
    const int* dst = edge + NE;

    const size_t N64 = (size_t)NN * HF;
    const int NGC = NBUCK * NBLKP;                       // 25088
    unsigned short* V16 = (unsigned short*)d_ws;         // N*64 bf16
    unsigned short* Hs = V16 + N64;                      // N*64 bf16
    float* rdeg = (float*)(Hs + N64);                    // N
    float* stats = rdeg + NN;                            // 128 (sum | sumsq)
    float* pool = stats + 128;                           // NG*64
    int* gcount = (int*)(pool + (size_t)NG * HF);        // NGC
    int* goff = gcount + NGC;                            // NGC
    int* bsum = goff + NGC;                              // 128
    int* ro = bsum + 128;                                // N+1
    int* tmp = ro + NN + 1;                              // E
    int* ss = tmp + NE;                                  // E

    // ---- CSR build (2-level bucket sort) ----
    kA_count<<<NBLKP, 256, 0, stream>>>(dst, gcount);
    const int nblk = (NGC + 1023) / 1024;                // 25
    k_scan1<<<nblk, 256, 0, stream>>>(gcount, goff, bsum, NGC);
    k_scan2<<<1, 128, 0, stream>>>(bsum, nblk);
    k_scan3g<<<(NGC + 255) / 256, 256, 0, stream>>>(goff, bsum, NGC);
    kB_part<<<NBLKP, 256, 0, stream>>>(src, dst, goff, tmp);
    kC_build<<<NBUCK, 256, 0, stream>>>(goff, tmp, ss, ro, rdeg, NE);

    hipMemsetAsync(pool, 0, (size_t)NG * HF * sizeof(float), stream);

    const float* gW[3] = {W1, W2, W3};
    const float* gb[3] = {b1, b2, b3};
    const float* gg[3] = {g1, g2, g3};
    const float* gbe[3] = {be1, be2, be3};

    const int tileblk = (NN + 63) / 64;
    const int aggblk = (NN + 15) / 16;        // 4 nodes/wave * 4 waves
    const int poolblk = ((NN + 63) / 64 + 3) / 4;

    for (int l = 0; l < 3; ++l) {
        if (l == 0)
            k_gemm_lds<INF_, false><<<tileblk, 256, 0, stream>>>(x, (const unsigned short*)0,
                                                                 gW[0], gb[0], rdeg, stats,
                                                                 gg[0], gbe[0], Hs, NN);
        else
            k_gemm_lds<HF, true><<<tileblk, 256, 0, stream>>>((const float*)0, V16,
                                                              gW[l], gb[l], rdeg, stats,
                                                              gg[l - 1], gbe[l - 1], Hs, NN);
        k_agg<<<aggblk, 256, 0, stream>>>(ro, ss, Hs, rdeg, V16, NN);
        hipMemsetAsync(stats, 0, 128 * sizeof(float), stream);
        k_stats<<<1024, 256, 0, stream>>>(V16, stats, NN);
        if (l == 2)
            k_pool2<<<poolblk, 256, 0, stream>>>(V16, stats, gg[2], gbe[2], batch, pool, NN);
    }

    k_cls<<<NG, HF, 0, stream>>>(pool, Wc1, bc1, Wc2, bc2, out);
}

// Round 7
// 442.965 us; speedup vs baseline: 2.1557x; 1.0390x over previous
//
#include <hip/hip_runtime.h>
#include <hip/hip_bf16.h>

// GCN graph classifier: 3x (GCNConv -> BN -> ReLU) -> sum-pool -> MLP head.
//   Hs[i] = (relu_bn(x[i])@W.T + b) * rdeg[i]   (MFMA bf16 gemm, prev-layer BN fused in staging)
//   V[d]  = rdeg[d]*(Hs[d] + sum_in Hs[s])      (CSR gather; 4ch/lane, 4 nodes/wave; bf16 out)
// CSR via 2-level bucket sort (line-dense writes, LDS atomics only).
// Pool = run-flush segmented sum over sorted batch (wave per 64 rows).

#define NN 100000
#define NE 1600000
#define INF_ 128
#define HF 64
#define OUTF 10
#define NG 128
#define NBUCK 196     // ceil(NN/512)
#define NBLKP 128     // partition blocks; NE % NBLKP == 0 -> 12500 edges/block
#define CPB (NE / NBLKP)

typedef short bf16x8 __attribute__((ext_vector_type(8)));
typedef float f32x4 __attribute__((ext_vector_type(4)));

static __device__ __forceinline__ unsigned short f2bf(float x) {
    unsigned int b = __float_as_uint(x);
    b += 0x7FFFu + ((b >> 16) & 1u);   // RNE
    return (unsigned short)(b >> 16);
}
static __device__ __forceinline__ float bf2f(unsigned short u) {
    return __uint_as_float(((unsigned int)u) << 16);
}
static __device__ __forceinline__ float bflo(unsigned int u) {
    return __uint_as_float(u << 16);
}
static __device__ __forceinline__ float bfhi(unsigned int u) {
    return __uint_as_float(u & 0xffff0000u);
}

// ---- CSR build ----
__global__ __launch_bounds__(256) void kA_count(const int* __restrict__ dst,
                                                int* __restrict__ gcount) {
    __shared__ int cnt[256];
    int t = threadIdx.x, blk = blockIdx.x;
    cnt[t] = 0;
    __syncthreads();
    int beg = blk * CPB, end = beg + CPB;
    for (int i = beg + t; i < end; i += 256) atomicAdd(&cnt[dst[i] >> 9], 1);
    __syncthreads();
    if (t < NBUCK) gcount[t * NBLKP + blk] = cnt[t];
}

__global__ void k_scan1(const int* __restrict__ cnt, int* __restrict__ ro,
                        int* __restrict__ bsum, int n) {
    __shared__ int ts[256];
    int base = blockIdx.x * 1024 + threadIdx.x * 4;
    int v[4], s = 0;
#pragma unroll
    for (int k = 0; k < 4; ++k) {
        int idx = base + k;
        v[k] = (idx < n) ? cnt[idx] : 0;
        s += v[k];
    }
    ts[threadIdx.x] = s;
    __syncthreads();
    for (int off = 1; off < 256; off <<= 1) {
        int t = (threadIdx.x >= off) ? ts[threadIdx.x - off] : 0;
        __syncthreads();
        ts[threadIdx.x] += t;
        __syncthreads();
    }
    int ex = ts[threadIdx.x] - s;
    if (threadIdx.x == 255) bsum[blockIdx.x] = ts[255];
#pragma unroll
    for (int k = 0; k < 4; ++k) {
        int idx = base + k;
        if (idx < n) ro[idx] = ex;
        ex += v[k];
    }
}

__global__ void k_scan2(int* __restrict__ bsum, int nb) {
    __shared__ int ts[128];
    int i = threadIdx.x;
    int v = (i < nb) ? bsum[i] : 0;
    ts[i] = v;
    __syncthreads();
    for (int off = 1; off < 128; off <<= 1) {
        int t = (i >= off) ? ts[i - off] : 0;
        __syncthreads();
        ts[i] += t;
        __syncthreads();
    }
    if (i < nb) bsum[i] = ts[i] - v;
}

__global__ void k_scan3g(int* __restrict__ goff, const int* __restrict__ bsum, int n) {
    int i = blockIdx.x * 256 + threadIdx.x;
    if (i < n) goff[i] += bsum[i >> 10];
}

__global__ __launch_bounds__(256) void kB_part(const int* __restrict__ src,
                                               const int* __restrict__ dst,
                                               const int* __restrict__ goff,
                                               int* __restrict__ tmp) {
    __shared__ int cur[NBUCK];
    int t = threadIdx.x, blk = blockIdx.x;
    if (t < NBUCK) cur[t] = goff[t * NBLKP + blk];
    __syncthreads();
    int beg = blk * CPB, end = beg + CPB;
    for (int i = beg + t; i < end; i += 256) {
        int d = dst[i];
        int pos = atomicAdd(&cur[d >> 9], 1);
        tmp[pos] = ((d & 511) << 17) | src[i];
    }
}

__global__ __launch_bounds__(256) void kC_build(const int* __restrict__ goff,
                                                int* __restrict__ tmp,
                                                int* __restrict__ ss,
                                                int* __restrict__ ro,
                                                float* __restrict__ rdeg, int E) {
    __shared__ int cnt[512];
    __shared__ int ts[256];
    __shared__ int cur[512];
    int t = threadIdx.x, b = blockIdx.x;
    int beg = goff[b * NBLKP];
    int end = (b + 1 < NBUCK) ? goff[(b + 1) * NBLKP] : E;
    cnt[t] = 0;
    cnt[t + 256] = 0;
    __syncthreads();
    for (int i = beg + t; i < end; i += 256) atomicAdd(&cnt[tmp[i] >> 17], 1);
    __syncthreads();
    int a0 = cnt[2 * t], a1 = cnt[2 * t + 1], s = a0 + a1;
    ts[t] = s;
    __syncthreads();
    for (int off = 1; off < 256; off <<= 1) {
        int v = (t >= off) ? ts[t - off] : 0;
        __syncthreads();
        ts[t] += v;
        __syncthreads();
    }
    int ex = ts[t] - s;
    int p0 = beg + ex, p1 = beg + ex + a0;
    cur[2 * t] = p0;
    cur[2 * t + 1] = p1;
    int node0 = (b << 9) + 2 * t;
    if (node0 < NN) { ro[node0] = p0; rdeg[node0] = rsqrtf((float)a0 + 1.f); }
    else if (node0 == NN) ro[NN] = p0;
    int node1 = node0 + 1;
    if (node1 < NN) { ro[node1] = p1; rdeg[node1] = rsqrtf((float)a1 + 1.f); }
    else if (node1 == NN) ro[NN] = p1;
    __syncthreads();
    for (int i = beg + t; i < end; i += 256) {
        int p = tmp[i];
        int pos = atomicAdd(&cur[p >> 17], 1);
        ss[pos] = p & 0x1FFFF;
    }
}

// ---- MFMA GEMM: 64-row tile, 256 threads (4 waves), wave w -> rows [16w,16w+16).
// Hs[row][ch] = (sum_k Xbn[row][k]*W[ch][k] + bias[ch]) * rdeg[row], bf16 out.
// W fragments preloaded to VGPRs from global (bf16-rounded); X staged in LDS bf16
// with XOR swizzle (byte ^= (row&7)<<4). k-interleave per frag elem i, lane group
// g=lane>>4: k = 4g + (i&3) + 16*(i>>2) — any bijection works if used for BOTH
// operands; C/D layout (HW-verified): row = 4*(lane>>4)+reg, col = lane&15.
template<int K, bool BN>
__global__ __launch_bounds__(256) void k_gemm_mfma(const float* __restrict__ Xf,
                                                   const unsigned short* __restrict__ Xh,
                                                   const float* __restrict__ W,
                                                   const float* __restrict__ bias,
                                                   const float* __restrict__ rdeg,
                                                   const float* __restrict__ stats,
                                                   const float* __restrict__ g,
                                                   const float* __restrict__ be,
                                                   unsigned short* __restrict__ Hs, int n) {
    constexpr int KB = K / 32;       // k-steps
    constexpr int RB = K * 2;        // LDS row bytes (bf16)
    __shared__ __align__(16) char raw[64 * 68 * 4];  // stage bf16[64][K] / out f32[64][68]
    __shared__ float sa_l[64], sb_l[64];
    const int t = threadIdx.x;
    const int w = t >> 6;
    const int c = t & 15;            // lane&15
    const int gq = (t >> 4) & 3;     // lane>>4
    const int r0 = blockIdx.x * 64;

    if (BN && t < 64) {
        float n_ = (float)NN;
        float mu = stats[t] / n_;
        float var = stats[64 + t] / n_ - mu * mu;
        float a = g[t] * rsqrtf(var + 1e-5f);
        sa_l[t] = a;
        sb_l[t] = be[t] - mu * a;
    }

    // W fragments: wf[n][kb], b-operand: lane c = output channel 16n+c, elems over k.
    bf16x8 wf[4][KB];
#pragma unroll
    for (int nn_ = 0; nn_ < 4; ++nn_) {
        const float* wr = W + (size_t)(16 * nn_ + c) * K;
#pragma unroll
        for (int kb = 0; kb < KB; ++kb) {
            bf16x8 v;
#pragma unroll
            for (int i = 0; i < 8; ++i) {
                int k = kb * 32 + 4 * gq + (i & 3) + 16 * (i >> 2);
                v[i] = (short)f2bf(wr[k]);
            }
            wf[nn_][kb] = v;
        }
    }
    __syncthreads();  // sa_l ready (and stage buffer free)

    // Stage X tile: thread t handles row r=t>>2, channel chunk q=t&3 (K/4 channels).
    {
        int r = t >> 2, q = t & 3;
        int row = r0 + r;
        int x_swz = (r & 7) << 4;
        if (BN) {                     // K==64: 16 ch per thread from bf16 V
            int ch0 = q * 16;
            uint4 u0 = make_uint4(0, 0, 0, 0), u1 = make_uint4(0, 0, 0, 0);
            if (row < n) {
                const uint4* p = (const uint4*)(Xh + (size_t)row * 64 + ch0);
                u0 = p[0];
                u1 = p[1];
            }
            unsigned int uin[8] = {u0.x, u0.y, u0.z, u0.w, u1.x, u1.y, u1.z, u1.w};
            unsigned int uo[8];
#pragma unroll
            for (int j = 0; j < 8; ++j) {
                int chl = ch0 + 2 * j, chh = chl + 1;
                float v0 = fmaxf(fmaf(sa_l[chl], bflo(uin[j]), sb_l[chl]), 0.f);
                float v1 = fmaxf(fmaf(sa_l[chh], bfhi(uin[j]), sb_l[chh]), 0.f);
                uo[j] = (unsigned int)f2bf(v0) | ((unsigned int)f2bf(v1) << 16);
            }
            int b0 = r * RB + q * 32;
            *(uint4*)(raw + ((b0) ^ x_swz)) = make_uint4(uo[0], uo[1], uo[2], uo[3]);
            *(uint4*)(raw + ((b0 + 16) ^ x_swz)) = make_uint4(uo[4], uo[5], uo[6], uo[7]);
        } else {                      // K==128: 32 ch per thread from f32 x
            int ch0 = q * 32;
#pragma unroll
            for (int j2 = 0; j2 < 4; ++j2) {
                float4 a = make_float4(0.f, 0.f, 0.f, 0.f), b = make_float4(0.f, 0.f, 0.f, 0.f);
                if (row < n) {
                    const float4* p = (const float4*)(Xf + (size_t)row * K + ch0 + j2 * 8);
                    a = p[0];
                    b = p[1];
                }
                unsigned int q0 = (unsigned int)f2bf(a.x) | ((unsigned int)f2bf(a.y) << 16);
                unsigned int q1 = (unsigned int)f2bf(a.z) | ((unsigned int)f2bf(a.w) << 16);
                unsigned int q2 = (unsigned int)f2bf(b.x) | ((unsigned int)f2bf(b.y) << 16);
                unsigned int q3 = (unsigned int)f2bf(b.z) | ((unsigned int)f2bf(b.w) << 16);
                int b0 = r * RB + ch0 * 2 + j2 * 16;
                *(uint4*)(raw + (b0 ^ x_swz)) = make_uint4(q0, q1, q2, q3);
            }
        }
    }
    __syncthreads();

    // A fragments from LDS + MFMA.
    bf16x8 af[KB];
    {
        int r = 16 * w + c;
        int rb = r * RB;
        int swz = (r & 7) << 4;
#pragma unroll
        for (int kb = 0; kb < KB; ++kb) {
            int off = rb + kb * 64 + gq * 8;
            uint2 u0 = *(const uint2*)(raw + (off ^ swz));
            uint2 u1 = *(const uint2*)(raw + ((off + 32) ^ swz));
            union { uint4 u; bf16x8 v; } cv;
            cv.u = make_uint4(u0.x, u0.y, u1.x, u1.y);
            af[kb] = cv.v;
        }
    }
    f32x4 acc[4];
#pragma unroll
    for (int nn_ = 0; nn_ < 4; ++nn_) {
        acc[nn_] = (f32x4){0.f, 0.f, 0.f, 0.f};
#pragma unroll
        for (int kb = 0; kb < KB; ++kb)
            acc[nn_] = __builtin_amdgcn_mfma_f32_16x16x32_bf16(af[kb], wf[nn_][kb], acc[nn_], 0, 0, 0);
    }

    // Epilogue: (acc + bias) * rdeg -> LDS f32 [64][68] -> coalesced bf16 store.
    __syncthreads();
    float* outb = (float*)raw;
    float rv[4];
#pragma unroll
    for (int i = 0; i < 4; ++i) {
        int rg = r0 + 16 * w + 4 * gq + i;
        rv[i] = (rg < n) ? rdeg[rg] : 0.f;
    }
#pragma unroll
    for (int nn_ = 0; nn_ < 4; ++nn_) {
        int col = 16 * nn_ + c;
        float bz = bias[col];
#pragma unroll
        for (int i = 0; i < 4; ++i)
            outb[(16 * w + 4 * gq + i) * 68 + col] = (acc[nn_][i] + bz) * rv[i];
    }
    __syncthreads();
    {
        int r = t >> 2, q = t & 3;
        int row = r0 + r;
        if (row < n) {
            const float* src = outb + r * 68 + q * 16;
            unsigned int u[8];
#pragma unroll
            for (int j = 0; j < 8; ++j)
                u[j] = (unsigned int)f2bf(src[2 * j]) | ((unsigned int)f2bf(src[2 * j + 1]) << 16);
            uint4* p = (uint4*)(Hs + (size_t)row * HF + q * 16);
            p[0] = make_uint4(u[0], u[1], u[2], u[3]);
            p[1] = make_uint4(u[4], u[5], u[6], u[7]);
        }
    }
}

// Aggregation: quarter-wave per node (16 lanes x 4 ch via uint2), 4 nodes/wave.
__global__ __launch_bounds__(256) void k_agg(const int* __restrict__ ro,
                                             const int* __restrict__ ss,
                                             const unsigned short* __restrict__ Hs,
                                             const float* __restrict__ rdeg,
                                             unsigned short* __restrict__ V16, int n) {
    int wid = blockIdx.x * 4 + (threadIdx.x >> 6);
    int sub = (threadIdx.x >> 4) & 3;
    int c4 = (threadIdx.x & 15) * 4;
    int node = wid * 4 + sub;
    bool vn = node < n;
    int beg = 0, d = 0;
    if (vn) {
        beg = ro[node];
        d = ro[node + 1] - beg;
    }
    float4 acc = make_float4(0.f, 0.f, 0.f, 0.f);
    if (vn) {
        uint2 u = *(const uint2*)(Hs + ((size_t)node << 6) + c4);
        acc.x = bflo(u.x); acc.y = bfhi(u.x); acc.z = bflo(u.y); acc.w = bfhi(u.y);
    }
    int dm = d;
    dm = max(dm, __shfl_xor(dm, 16));
    dm = max(dm, __shfl_xor(dm, 32));
    int it = 0;
    for (; it + 1 < dm; it += 2) {
        bool a0 = it < d, a1 = it + 1 < d;
        int s0 = 0, s1 = 0;
        if (a0) s0 = ss[beg + it];
        if (a1) s1 = ss[beg + it + 1];
        uint2 u0 = make_uint2(0u, 0u), u1 = make_uint2(0u, 0u);
        if (a0) u0 = *(const uint2*)(Hs + ((size_t)s0 << 6) + c4);
        if (a1) u1 = *(const uint2*)(Hs + ((size_t)s1 << 6) + c4);
        acc.x += bflo(u0.x) + bflo(u1.x);
        acc.y += bfhi(u0.x) + bfhi(u1.x);
        acc.z += bflo(u0.y) + bflo(u1.y);
        acc.w += bfhi(u0.y) + bfhi(u1.y);
    }
    if (it < dm) {
        bool a0 = it < d;
        int s0 = 0;
        if (a0) s0 = ss[beg + it];
        uint2 u0 = make_uint2(0u, 0u);
        if (a0) u0 = *(const uint2*)(Hs + ((size_t)s0 << 6) + c4);
        acc.x += bflo(u0.x);
        acc.y += bfhi(u0.x);
        acc.z += bflo(u0.y);
        acc.w += bfhi(u0.y);
    }
    if (vn) {
        float rv = rdeg[node];
        unsigned int p0 = (unsigned int)f2bf(acc.x * rv) | ((unsigned int)f2bf(acc.y * rv) << 16);
        unsigned int p1 = (unsigned int)f2bf(acc.z * rv) | ((unsigned int)f2bf(acc.w * rv) << 16);
        *(uint2*)(V16 + ((size_t)node << 6) + c4) = make_uint2(p0, p1);
    }
}

__global__ void k_stats(const unsigned short* __restrict__ V16,
                        float* __restrict__ stats, int n) {
    __shared__ float ls[4][HF], lq[4][HF];
    int c = threadIdx.x & 63, w = threadIdx.x >> 6;
    float s = 0.f, q = 0.f;
    for (int r = blockIdx.x * 4 + w; r < n; r += gridDim.x * 4) {
        float v = bf2f(V16[(size_t)r * HF + c]);
        s += v;
        q += v * v;
    }
    ls[w][c] = s;
    lq[w][c] = q;
    __syncthreads();
    if (w == 0) {
        atomicAdd(&stats[c], ls[0][c] + ls[1][c] + ls[2][c] + ls[3][c]);
        atomicAdd(&stats[HF + c], lq[0][c] + lq[1][c] + lq[2][c] + lq[3][c]);
    }
}

// Pool: wave per 64 consecutive rows, run-flush atomics at graph boundaries.
__global__ __launch_bounds__(256) void k_pool2(const unsigned short* __restrict__ V16,
                                               const float* __restrict__ stats,
                                               const float* __restrict__ g,
                                               const float* __restrict__ be,
                                               const int* __restrict__ batch,
                                               float* __restrict__ pool, int n) {
    __shared__ float sa_l[64], sb_l[64];
    int t = threadIdx.x;
    if (t < 64) {
        float n_ = (float)NN;
        float mu = stats[t] / n_;
        float var = stats[64 + t] / n_ - mu * mu;
        float a = g[t] * rsqrtf(var + 1e-5f);
        sa_l[t] = a;
        sb_l[t] = be[t] - mu * a;
    }
    __syncthreads();
    int wid = blockIdx.x * 4 + (t >> 6);
    int r0 = wid * 64;
    if (r0 >= n) return;
    int lane = t & 63;
    float sa = sa_l[lane], sb = sb_l[lane];
    int rend = min(r0 + 64, n);
    int cur = batch[r0];
    float s = 0.f;
    for (int r = r0; r < rend; ++r) {
        int b = batch[r];
        if (b != cur) {
            atomicAdd(&pool[(size_t)cur * HF + lane], s);
            s = 0.f;
            cur = b;
        }
        float v = bf2f(V16[(size_t)r * HF + lane]);
        s += fmaxf(fmaf(sa, v, sb), 0.f);
    }
    atomicAdd(&pool[(size_t)cur * HF + lane], s);
}

__global__ void k_cls(const float* __restrict__ pool, const float* __restrict__ Wc1,
                      const float* __restrict__ bc1, const float* __restrict__ Wc2,
                      const float* __restrict__ bc2, float* __restrict__ out) {
    __shared__ float pl[HF], hr[HF];
    int g = blockIdx.x, c = threadIdx.x;
    pl[c] = pool[g * HF + c];
    __syncthreads();
    float h = bc1[c];
#pragma unroll
    for (int k = 0; k < HF; ++k) h = fmaf(pl[k], Wc1[c * HF + k], h);
    hr[c] = fmaxf(h, 0.f);
    __syncthreads();
    if (c < OUTF) {
        float o = bc2[c];
#pragma unroll
        for (int k = 0; k < HF; ++k) o = fmaf(hr[k], Wc2[c * HF + k], o);
        out[g * OUTF + c] = o;
    }
}

extern "C" void kernel_launch(void* const* d_in, const int* in_sizes, int n_in,
                              void* d_out, int out_size, void* d_ws, size_t ws_size,
                              hipStream_t stream) {
    const float* x = (const float*)d_in[0];
    const int* edge = (const int*)d_in[1];
    const int* batch = (const int*)d_in[2];
    const float* W1 = (const float*)d_in[3];
    const float* b1 = (const float*)d_in[4];
    const float* g1 = (const float*)d_in[5];
    const float* be1 = (const float*)d_in[6];
    const float* W2 = (const float*)d_in[7];
    const float* b2 = (const float*)d_in[8];
    const float* g2 = (const float*)d_in[9];
    const float* be2 = (const float*)d_in[10];
    const float* W3 = (const float*)d_in[11];
    const float* b3 = (const float*)d_in[12];
    const float* g3 = (const float*)d_in[13];
    const float* be3 = (const float*)d_in[14];
    const float* Wc1 = (const float*)d_in[15];
    const float* bc1 = (const float*)d_in[16];
    const float* Wc2 = (const float*)d_in[17];
    const float* bc2 = (const float*)d_in[18];
    float* out = (float*)d_out;

    const int* src = edge;
    const int* dst = edge + NE;

    const size_t N64 = (size_t)NN * HF;
    const int NGC = NBUCK * NBLKP;                       // 25088
    unsigned short* V16 = (unsigned short*)d_ws;         // N*64 bf16
    unsigned short* Hs = V16 + N64;                      // N*64 bf16
    float* rdeg = (float*)(Hs + N64);                    // N
    float* stats = rdeg + NN;                            // 128 (sum | sumsq)
    float* pool = stats + 128;                           // NG*64
    int* gcount = (int*)(pool + (size_t)NG * HF);        // NGC
    int* goff = gcount + NGC;                            // NGC
    int* bsum = goff + NGC;                              // 128
    int* ro = bsum + 128;                                // N+1
    int* tmp = ro + NN + 1;                              // E
    int* ss = tmp + NE;                                  // E

    // ---- CSR build (2-level bucket sort) ----
    kA_count<<<NBLKP, 256, 0, stream>>>(dst, gcount);
    const int nblk = (NGC + 1023) / 1024;                // 25
    k_scan1<<<nblk, 256, 0, stream>>>(gcount, goff, bsum, NGC);
    k_scan2<<<1, 128, 0, stream>>>(bsum, nblk);
    k_scan3g<<<(NGC + 255) / 256, 256, 0, stream>>>(goff, bsum, NGC);
    kB_part<<<NBLKP, 256, 0, stream>>>(src, dst, goff, tmp);
    kC_build<<<NBUCK, 256, 0, stream>>>(goff, tmp, ss, ro, rdeg, NE);

    hipMemsetAsync(pool, 0, (size_t)NG * HF * sizeof(float), stream);

    const float* gW[3] = {W1, W2, W3};
    const float* gb[3] = {b1, b2, b3};
    const float* gg[3] = {g1, g2, g3};
    const float* gbe[3] = {be1, be2, be3};

    const int tileblk = (NN + 63) / 64;
    const int aggblk = (NN + 15) / 16;        // 4 nodes/wave * 4 waves
    const int poolblk = ((NN + 63) / 64 + 3) / 4;

    for (int l = 0; l < 3; ++l) {
        if (l == 0)
            k_gemm_mfma<INF_, false><<<tileblk, 256, 0, stream>>>(x, (const unsigned short*)0,
                                                                  gW[0], gb[0], rdeg, stats,
                                                                  gg[0], gbe[0], Hs, NN);
        else
            k_gemm_mfma<HF, true><<<tileblk, 256, 0, stream>>>((const float*)0, V16,
                                                               gW[l], gb[l], rdeg, stats,
                                                               gg[l - 1], gbe[l - 1], Hs, NN);
        k_agg<<<aggblk, 256, 0, stream>>>(ro, ss, Hs, rdeg, V16, NN);
        hipMemsetAsync(stats, 0, 128 * sizeof(float), stream);
        k_stats<<<1024, 256, 0, stream>>>(V16, stats, NN);
        if (l == 2)
            k_pool2<<<poolblk, 256, 0, stream>>>(V16, stats, gg[2], gbe[2], batch, pool, NN);
    }

    k_cls<<<NG, HF, 0, stream>>>(pool, Wc1, bc1, Wc2, bc2, out);
}

// Round 8
// 419.926 us; speedup vs baseline: 2.2740x; 1.0549x over previous
//
#include <hip/hip_runtime.h>
#include <hip/hip_bf16.h>

// GCN graph classifier: 3x (GCNConv -> BN -> ReLU) -> sum-pool -> MLP head.
//   Hs[i] = (relu_bn(x[i])@W.T + b) * rdeg[i]   (MFMA bf16 gemm, prev-layer BN fused in staging)
//   V[d]  = rdeg[d]*(Hs[d] + sum_in Hs[s])      (CSR gather; 16-deep MLP batches; bf16 out)
// CSR via 2-level bucket sort (line-dense writes, LDS atomics only).
// Pool = run-flush segmented sum over sorted batch (wave per 64 rows).

#define NN 100000
#define NE 1600000
#define INF_ 128
#define HF 64
#define OUTF 10
#define NG 128
#define NBUCK 196     // ceil(NN/512)
#define NBLKP 128     // partition blocks; NE % NBLKP == 0 -> 12500 edges/block
#define CPB (NE / NBLKP)

typedef short bf16x8 __attribute__((ext_vector_type(8)));
typedef float f32x4 __attribute__((ext_vector_type(4)));

static __device__ __forceinline__ unsigned short f2bf(float x) {
    unsigned int b = __float_as_uint(x);
    b += 0x7FFFu + ((b >> 16) & 1u);   // RNE
    return (unsigned short)(b >> 16);
}
static __device__ __forceinline__ float bf2f(unsigned short u) {
    return __uint_as_float(((unsigned int)u) << 16);
}
static __device__ __forceinline__ float bflo(unsigned int u) {
    return __uint_as_float(u << 16);
}
static __device__ __forceinline__ float bfhi(unsigned int u) {
    return __uint_as_float(u & 0xffff0000u);
}

// ---- CSR build ----
__global__ __launch_bounds__(256) void kA_count(const int* __restrict__ dst,
                                                int* __restrict__ gcount) {
    __shared__ int cnt[256];
    int t = threadIdx.x, blk = blockIdx.x;
    cnt[t] = 0;
    __syncthreads();
    int beg = blk * CPB, end = beg + CPB;
    for (int i = beg + t; i < end; i += 256) atomicAdd(&cnt[dst[i] >> 9], 1);
    __syncthreads();
    if (t < NBUCK) gcount[t * NBLKP + blk] = cnt[t];
}

__global__ void k_scan1(const int* __restrict__ cnt, int* __restrict__ ro,
                        int* __restrict__ bsum, int n) {
    __shared__ int ts[256];
    int base = blockIdx.x * 1024 + threadIdx.x * 4;
    int v[4], s = 0;
#pragma unroll
    for (int k = 0; k < 4; ++k) {
        int idx = base + k;
        v[k] = (idx < n) ? cnt[idx] : 0;
        s += v[k];
    }
    ts[threadIdx.x] = s;
    __syncthreads();
    for (int off = 1; off < 256; off <<= 1) {
        int t = (threadIdx.x >= off) ? ts[threadIdx.x - off] : 0;
        __syncthreads();
        ts[threadIdx.x] += t;
        __syncthreads();
    }
    int ex = ts[threadIdx.x] - s;
    if (threadIdx.x == 255) bsum[blockIdx.x] = ts[255];
#pragma unroll
    for (int k = 0; k < 4; ++k) {
        int idx = base + k;
        if (idx < n) ro[idx] = ex;
        ex += v[k];
    }
}

__global__ void k_scan2(int* __restrict__ bsum, int nb) {
    __shared__ int ts[128];
    int i = threadIdx.x;
    int v = (i < nb) ? bsum[i] : 0;
    ts[i] = v;
    __syncthreads();
    for (int off = 1; off < 128; off <<= 1) {
        int t = (i >= off) ? ts[i - off] : 0;
        __syncthreads();
        ts[i] += t;
        __syncthreads();
    }
    if (i < nb) bsum[i] = ts[i] - v;
}

__global__ void k_scan3g(int* __restrict__ goff, const int* __restrict__ bsum, int n) {
    int i = blockIdx.x * 256 + threadIdx.x;
    if (i < n) goff[i] += bsum[i >> 10];
}

__global__ __launch_bounds__(256) void kB_part(const int* __restrict__ src,
                                               const int* __restrict__ dst,
                                               const int* __restrict__ goff,
                                               int* __restrict__ tmp) {
    __shared__ int cur[NBUCK];
    int t = threadIdx.x, blk = blockIdx.x;
    if (t < NBUCK) cur[t] = goff[t * NBLKP + blk];
    __syncthreads();
    int beg = blk * CPB, end = beg + CPB;
    for (int i = beg + t; i < end; i += 256) {
        int d = dst[i];
        int pos = atomicAdd(&cur[d >> 9], 1);
        tmp[pos] = ((d & 511) << 17) | src[i];
    }
}

__global__ __launch_bounds__(256) void kC_build(const int* __restrict__ goff,
                                                int* __restrict__ tmp,
                                                int* __restrict__ ss,
                                                int* __restrict__ ro,
                                                float* __restrict__ rdeg, int E) {
    __shared__ int cnt[512];
    __shared__ int ts[256];
    __shared__ int cur[512];
    int t = threadIdx.x, b = blockIdx.x;
    int beg = goff[b * NBLKP];
    int end = (b + 1 < NBUCK) ? goff[(b + 1) * NBLKP] : E;
    cnt[t] = 0;
    cnt[t + 256] = 0;
    __syncthreads();
    for (int i = beg + t; i < end; i += 256) atomicAdd(&cnt[tmp[i] >> 17], 1);
    __syncthreads();
    int a0 = cnt[2 * t], a1 = cnt[2 * t + 1], s = a0 + a1;
    ts[t] = s;
    __syncthreads();
    for (int off = 1; off < 256; off <<= 1) {
        int v = (t >= off) ? ts[t - off] : 0;
        __syncthreads();
        ts[t] += v;
        __syncthreads();
    }
    int ex = ts[t] - s;
    int p0 = beg + ex, p1 = beg + ex + a0;
    cur[2 * t] = p0;
    cur[2 * t + 1] = p1;
    int node0 = (b << 9) + 2 * t;
    if (node0 < NN) { ro[node0] = p0; rdeg[node0] = rsqrtf((float)a0 + 1.f); }
    else if (node0 == NN) ro[NN] = p0;
    int node1 = node0 + 1;
    if (node1 < NN) { ro[node1] = p1; rdeg[node1] = rsqrtf((float)a1 + 1.f); }
    else if (node1 == NN) ro[NN] = p1;
    __syncthreads();
    for (int i = beg + t; i < end; i += 256) {
        int p = tmp[i];
        int pos = atomicAdd(&cur[p >> 17], 1);
        ss[pos] = p & 0x1FFFF;
    }
}

// ---- MFMA GEMM: 64-row tile, 256 threads (4 waves), wave w -> rows [16w,16w+16).
template<int K, bool BN>
__global__ __launch_bounds__(256) void k_gemm_mfma(const float* __restrict__ Xf,
                                                   const unsigned short* __restrict__ Xh,
                                                   const float* __restrict__ W,
                                                   const float* __restrict__ bias,
                                                   const float* __restrict__ rdeg,
                                                   const float* __restrict__ stats,
                                                   const float* __restrict__ g,
                                                   const float* __restrict__ be,
                                                   unsigned short* __restrict__ Hs, int n) {
    constexpr int KB = K / 32;       // k-steps
    constexpr int RB = K * 2;        // LDS row bytes (bf16)
    __shared__ __align__(16) char raw[64 * 68 * 4];  // stage bf16[64][K] / out f32[64][68]
    __shared__ float sa_l[64], sb_l[64];
    const int t = threadIdx.x;
    const int w = t >> 6;
    const int c = t & 15;            // lane&15
    const int gq = (t >> 4) & 3;     // lane>>4
    const int r0 = blockIdx.x * 64;

    if (BN && t < 64) {
        float n_ = (float)NN;
        float mu = stats[t] / n_;
        float var = stats[64 + t] / n_ - mu * mu;
        float a = g[t] * rsqrtf(var + 1e-5f);
        sa_l[t] = a;
        sb_l[t] = be[t] - mu * a;
    }

    // W fragments: b-operand, lane c = output channel 16n+c, elems over k.
    bf16x8 wf[4][KB];
#pragma unroll
    for (int nn_ = 0; nn_ < 4; ++nn_) {
        const float* wr = W + (size_t)(16 * nn_ + c) * K;
#pragma unroll
        for (int kb = 0; kb < KB; ++kb) {
            bf16x8 v;
#pragma unroll
            for (int i = 0; i < 8; ++i) {
                int k = kb * 32 + 4 * gq + (i & 3) + 16 * (i >> 2);
                v[i] = (short)f2bf(wr[k]);
            }
            wf[nn_][kb] = v;
        }
    }
    __syncthreads();  // sa_l ready (and stage buffer free)

    // Stage X tile: thread t handles row r=t>>2, channel chunk q=t&3.
    {
        int r = t >> 2, q = t & 3;
        int row = r0 + r;
        int x_swz = (r & 7) << 4;
        if (BN) {                     // K==64: 16 ch per thread from bf16 V
            int ch0 = q * 16;
            uint4 u0 = make_uint4(0, 0, 0, 0), u1 = make_uint4(0, 0, 0, 0);
            if (row < n) {
                const uint4* p = (const uint4*)(Xh + (size_t)row * 64 + ch0);
                u0 = p[0];
                u1 = p[1];
            }
            unsigned int uin[8] = {u0.x, u0.y, u0.z, u0.w, u1.x, u1.y, u1.z, u1.w};
            unsigned int uo[8];
#pragma unroll
            for (int j = 0; j < 8; ++j) {
                int chl = ch0 + 2 * j, chh = chl + 1;
                float v0 = fmaxf(fmaf(sa_l[chl], bflo(uin[j]), sb_l[chl]), 0.f);
                float v1 = fmaxf(fmaf(sa_l[chh], bfhi(uin[j]), sb_l[chh]), 0.f);
                uo[j] = (unsigned int)f2bf(v0) | ((unsigned int)f2bf(v1) << 16);
            }
            int b0 = r * RB + q * 32;
            *(uint4*)(raw + ((b0) ^ x_swz)) = make_uint4(uo[0], uo[1], uo[2], uo[3]);
            *(uint4*)(raw + ((b0 + 16) ^ x_swz)) = make_uint4(uo[4], uo[5], uo[6], uo[7]);
        } else {                      // K==128: 32 ch per thread from f32 x
            int ch0 = q * 32;
#pragma unroll
            for (int j2 = 0; j2 < 4; ++j2) {
                float4 a = make_float4(0.f, 0.f, 0.f, 0.f), b = make_float4(0.f, 0.f, 0.f, 0.f);
                if (row < n) {
                    const float4* p = (const float4*)(Xf + (size_t)row * K + ch0 + j2 * 8);
                    a = p[0];
                    b = p[1];
                }
                unsigned int q0 = (unsigned int)f2bf(a.x) | ((unsigned int)f2bf(a.y) << 16);
                unsigned int q1 = (unsigned int)f2bf(a.z) | ((unsigned int)f2bf(a.w) << 16);
                unsigned int q2 = (unsigned int)f2bf(b.x) | ((unsigned int)f2bf(b.y) << 16);
                unsigned int q3 = (unsigned int)f2bf(b.z) | ((unsigned int)f2bf(b.w) << 16);
                int b0 = r * RB + ch0 * 2 + j2 * 16;
                *(uint4*)(raw + (b0 ^ x_swz)) = make_uint4(q0, q1, q2, q3);
            }
        }
    }
    __syncthreads();

    // A fragments from LDS + MFMA.
    bf16x8 af[KB];
    {
        int r = 16 * w + c;
        int rb = r * RB;
        int swz = (r & 7) << 4;
#pragma unroll
        for (int kb = 0; kb < KB; ++kb) {
            int off = rb + kb * 64 + gq * 8;
            uint2 u0 = *(const uint2*)(raw + (off ^ swz));
            uint2 u1 = *(const uint2*)(raw + ((off + 32) ^ swz));
            union { uint4 u; bf16x8 v; } cv;
            cv.u = make_uint4(u0.x, u0.y, u1.x, u1.y);
            af[kb] = cv.v;
        }
    }
    f32x4 acc[4];
#pragma unroll
    for (int nn_ = 0; nn_ < 4; ++nn_) {
        acc[nn_] = (f32x4){0.f, 0.f, 0.f, 0.f};
#pragma unroll
        for (int kb = 0; kb < KB; ++kb)
            acc[nn_] = __builtin_amdgcn_mfma_f32_16x16x32_bf16(af[kb], wf[nn_][kb], acc[nn_], 0, 0, 0);
    }

    // Epilogue: (acc + bias) * rdeg -> LDS f32 [64][68] -> coalesced bf16 store.
    __syncthreads();
    float* outb = (float*)raw;
    float rv[4];
#pragma unroll
    for (int i = 0; i < 4; ++i) {
        int rg = r0 + 16 * w + 4 * gq + i;
        rv[i] = (rg < n) ? rdeg[rg] : 0.f;
    }
#pragma unroll
    for (int nn_ = 0; nn_ < 4; ++nn_) {
        int col = 16 * nn_ + c;
        float bz = bias[col];
#pragma unroll
        for (int i = 0; i < 4; ++i)
            outb[(16 * w + 4 * gq + i) * 68 + col] = (acc[nn_][i] + bz) * rv[i];
    }
    __syncthreads();
    {
        int r = t >> 2, q = t & 3;
        int row = r0 + r;
        if (row < n) {
            const float* src = outb + r * 68 + q * 16;
            unsigned int u[8];
#pragma unroll
            for (int j = 0; j < 8; ++j)
                u[j] = (unsigned int)f2bf(src[2 * j]) | ((unsigned int)f2bf(src[2 * j + 1]) << 16);
            uint4* p = (uint4*)(Hs + (size_t)row * HF + q * 16);
            p[0] = make_uint4(u[0], u[1], u[2], u[3]);
            p[1] = make_uint4(u[4], u[5], u[6], u[7]);
        }
    }
}

// Aggregation: quarter-wave per node (16 lanes x 4 ch via uint2), 4 nodes/wave.
// 16-deep MLP: lane-parallel index batch load, shfl broadcast, 16 gathers in flight.
__global__ __launch_bounds__(256) void k_agg(const int* __restrict__ ro,
                                             const int* __restrict__ ss,
                                             const unsigned short* __restrict__ Hs,
                                             const float* __restrict__ rdeg,
                                             unsigned short* __restrict__ V16, int n) {
    int wid = blockIdx.x * 4 + (threadIdx.x >> 6);
    int lane = threadIdx.x & 63;
    int sub = lane >> 4;           // quarter id (node slot)
    int lq = lane & 15;            // lane within quarter
    int c4 = lq * 4;               // 4 channels per lane
    int node = wid * 4 + sub;
    bool vn = node < n;
    int beg = 0, d = 0;
    if (vn) {
        beg = ro[node];
        d = ro[node + 1] - beg;
    }
    float4 acc = make_float4(0.f, 0.f, 0.f, 0.f);
    if (vn) {
        uint2 u = *(const uint2*)(Hs + ((size_t)node << 6) + c4);
        acc.x = bflo(u.x); acc.y = bfhi(u.x); acc.z = bflo(u.y); acc.w = bfhi(u.y);
    }
    // wave-uniform max degree (d uniform within quarter)
    int dm = d;
    dm = max(dm, __shfl_xor(dm, 16));
    dm = max(dm, __shfl_xor(dm, 32));
    for (int it = 0; it < dm; it += 16) {
        int myidx = (it + lq < d) ? ss[beg + it + lq] : -1;
#pragma unroll
        for (int k = 0; k < 16; ++k) {
            if (it + k >= dm) break;                    // wave-uniform scalar branch
            int s = __shfl(myidx, (sub << 4) + k);
            if (s >= 0) {
                uint2 u = *(const uint2*)(Hs + ((size_t)s << 6) + c4);
                acc.x += bflo(u.x);
                acc.y += bfhi(u.x);
                acc.z += bflo(u.y);
                acc.w += bfhi(u.y);
            }
        }
    }
    if (vn) {
        float rv = rdeg[node];
        unsigned int p0 = (unsigned int)f2bf(acc.x * rv) | ((unsigned int)f2bf(acc.y * rv) << 16);
        unsigned int p1 = (unsigned int)f2bf(acc.z * rv) | ((unsigned int)f2bf(acc.w * rv) << 16);
        *(uint2*)(V16 + ((size_t)node << 6) + c4) = make_uint2(p0, p1);
    }
}

__global__ void k_stats(const unsigned short* __restrict__ V16,
                        float* __restrict__ statsOut, int n) {
    __shared__ float ls[4][HF], lq[4][HF];
    int c = threadIdx.x & 63, w = threadIdx.x >> 6;
    float s = 0.f, q = 0.f;
    for (int r = blockIdx.x * 4 + w; r < n; r += gridDim.x * 4) {
        float v = bf2f(V16[(size_t)r * HF + c]);
        s += v;
        q += v * v;
    }
    ls[w][c] = s;
    lq[w][c] = q;
    __syncthreads();
    if (w == 0) {
        atomicAdd(&statsOut[c], ls[0][c] + ls[1][c] + ls[2][c] + ls[3][c]);
        atomicAdd(&statsOut[HF + c], lq[0][c] + lq[1][c] + lq[2][c] + lq[3][c]);
    }
}

// Pool: wave per 64 consecutive rows, run-flush atomics at graph boundaries.
__global__ __launch_bounds__(256) void k_pool2(const unsigned short* __restrict__ V16,
                                               const float* __restrict__ stats,
                                               const float* __restrict__ g,
                                               const float* __restrict__ be,
                                               const int* __restrict__ batch,
                                               float* __restrict__ pool, int n) {
    __shared__ float sa_l[64], sb_l[64];
    int t = threadIdx.x;
    if (t < 64) {
        float n_ = (float)NN;
        float mu = stats[t] / n_;
        float var = stats[64 + t] / n_ - mu * mu;
        float a = g[t] * rsqrtf(var + 1e-5f);
        sa_l[t] = a;
        sb_l[t] = be[t] - mu * a;
    }
    __syncthreads();
    int wid = blockIdx.x * 4 + (t >> 6);
    int r0 = wid * 64;
    if (r0 >= n) return;
    int lane = t & 63;
    float sa = sa_l[lane], sb = sb_l[lane];
    int rend = min(r0 + 64, n);
    int cur = batch[r0];
    float s = 0.f;
    for (int r = r0; r < rend; ++r) {
        int b = batch[r];
        if (b != cur) {
            atomicAdd(&pool[(size_t)cur * HF + lane], s);
            s = 0.f;
            cur = b;
        }
        float v = bf2f(V16[(size_t)r * HF + lane]);
        s += fmaxf(fmaf(sa, v, sb), 0.f);
    }
    atomicAdd(&pool[(size_t)cur * HF + lane], s);
}

__global__ void k_cls(const float* __restrict__ pool, const float* __restrict__ Wc1,
                      const float* __restrict__ bc1, const float* __restrict__ Wc2,
                      const float* __restrict__ bc2, float* __restrict__ out) {
    __shared__ float pl[HF], hr[HF];
    int g = blockIdx.x, c = threadIdx.x;
    pl[c] = pool[g * HF + c];
    __syncthreads();
    float h = bc1[c];
#pragma unroll
    for (int k = 0; k < HF; ++k) h = fmaf(pl[k], Wc1[c * HF + k], h);
    hr[c] = fmaxf(h, 0.f);
    __syncthreads();
    if (c < OUTF) {
        float o = bc2[c];
#pragma unroll
        for (int k = 0; k < HF; ++k) o = fmaf(hr[k], Wc2[c * HF + k], o);
        out[g * OUTF + c] = o;
    }
}

extern "C" void kernel_launch(void* const* d_in, const int* in_sizes, int n_in,
                              void* d_out, int out_size, void* d_ws, size_t ws_size,
                              hipStream_t stream) {
    const float* x = (const float*)d_in[0];
    const int* edge = (const int*)d_in[1];
    const int* batch = (const int*)d_in[2];
    const float* W1 = (const float*)d_in[3];
    const float* b1 = (const float*)d_in[4];
    const float* g1 = (const float*)d_in[5];
    const float* be1 = (const float*)d_in[6];
    const float* W2 = (const float*)d_in[7];
    const float* b2 = (const float*)d_in[8];
    const float* g2 = (const float*)d_in[9];
    const float* be2 = (const float*)d_in[10];
    const float* W3 = (const float*)d_in[11];
    const float* b3 = (const float*)d_in[12];
    const float* g3 = (const float*)d_in[13];
    const float* be3 = (const float*)d_in[14];
    const float* Wc1 = (const float*)d_in[15];
    const float* bc1 = (const float*)d_in[16];
    const float* Wc2 = (const float*)d_in[17];
    const float* bc2 = (const float*)d_in[18];
    float* out = (float*)d_out;

    const int* src = edge;
    const int* dst = edge + NE;

    const size_t N64 = (size_t)NN * HF;
    const int NGC = NBUCK * NBLKP;                       // 25088
    unsigned short* V16 = (unsigned short*)d_ws;         // N*64 bf16
    unsigned short* Hs = V16 + N64;                      // N*64 bf16
    float* rdeg = (float*)(Hs + N64);                    // N
    float* stats = rdeg + NN;                            // 3*128 (per-layer sum|sumsq)
    float* pool = stats + 384;                           // NG*64 (contiguous w/ stats)
    int* gcount = (int*)(pool + (size_t)NG * HF);        // NGC
    int* goff = gcount + NGC;                            // NGC
    int* bsum = goff + NGC;                              // 128
    int* ro = bsum + 128;                                // N+1
    int* tmp = ro + NN + 1;                              // E
    int* ss = tmp + NE;                                  // E

    // ---- CSR build (2-level bucket sort) ----
    kA_count<<<NBLKP, 256, 0, stream>>>(dst, gcount);
    const int nblk = (NGC + 1023) / 1024;                // 25
    k_scan1<<<nblk, 256, 0, stream>>>(gcount, goff, bsum, NGC);
    k_scan2<<<1, 128, 0, stream>>>(bsum, nblk);
    k_scan3g<<<(NGC + 255) / 256, 256, 0, stream>>>(goff, bsum, NGC);
    kB_part<<<NBLKP, 256, 0, stream>>>(src, dst, goff, tmp);
    kC_build<<<NBUCK, 256, 0, stream>>>(goff, tmp, ss, ro, rdeg, NE);

    // one memset covers stats[3][128] + pool
    hipMemsetAsync(stats, 0, (384 + (size_t)NG * HF) * sizeof(float), stream);

    const float* gW[3] = {W1, W2, W3};
    const float* gb[3] = {b1, b2, b3};
    const float* gg[3] = {g1, g2, g3};
    const float* gbe[3] = {be1, be2, be3};

    const int tileblk = (NN + 63) / 64;
    const int aggblk = (NN + 15) / 16;        // 4 nodes/wave * 4 waves
    const int poolblk = ((NN + 63) / 64 + 3) / 4;

    for (int l = 0; l < 3; ++l) {
        if (l == 0)
            k_gemm_mfma<INF_, false><<<tileblk, 256, 0, stream>>>(x, (const unsigned short*)0,
                                                                  gW[0], gb[0], rdeg, stats,
                                                                  gg[0], gbe[0], Hs, NN);
        else
            k_gemm_mfma<HF, true><<<tileblk, 256, 0, stream>>>((const float*)0, V16,
                                                               gW[l], gb[l], rdeg,
                                                               stats + 128 * (l - 1),
                                                               gg[l - 1], gbe[l - 1], Hs, NN);
        k_agg<<<aggblk, 256, 0, stream>>>(ro, ss, Hs, rdeg, V16, NN);
        k_stats<<<1024, 256, 0, stream>>>(V16, stats + 128 * l, NN);
        if (l == 2)
            k_pool2<<<poolblk, 256, 0, stream>>>(V16, stats + 256, gg[2], gbe[2], batch, pool, NN);
    }

    k_cls<<<NG, HF, 0, stream>>>(pool, Wc1, bc1, Wc2, bc2, out);
}

// Round 9
// 373.881 us; speedup vs baseline: 2.5540x; 1.1232x over previous
//
#include <hip/hip_runtime.h>
#include <hip/hip_bf16.h>

// GCN graph classifier: 3x (GCNConv -> BN -> ReLU) -> sum-pool -> MLP head.
//   Hs[i] = (relu_bn(x[i])@W.T + b) * rdeg[i]   (MFMA bf16 gemm, prev-layer BN fused in staging)
//   V[d]  = rdeg[d]*(Hs[d] + sum_in Hs[s])      (CSR gather; branch-free 16-deep MLP; bf16 out)
// CSR via 2-level bucket sort (line-dense writes, LDS atomics only).
// Pool = run-flush segmented sum over sorted batch (wave per 64 rows).

#define NN 100000
#define NE 1600000
#define INF_ 128
#define HF 64
#define OUTF 10
#define NG 128
#define NBUCK 196     // ceil(NN/512)
#define NBLKP 128     // partition blocks; NE % NBLKP == 0 -> 12500 edges/block
#define CPB (NE / NBLKP)

typedef short bf16x8 __attribute__((ext_vector_type(8)));
typedef float f32x4 __attribute__((ext_vector_type(4)));

static __device__ __forceinline__ unsigned short f2bf(float x) {
    unsigned int b = __float_as_uint(x);
    b += 0x7FFFu + ((b >> 16) & 1u);   // RNE
    return (unsigned short)(b >> 16);
}
static __device__ __forceinline__ float bf2f(unsigned short u) {
    return __uint_as_float(((unsigned int)u) << 16);
}
static __device__ __forceinline__ float bflo(unsigned int u) {
    return __uint_as_float(u << 16);
}
static __device__ __forceinline__ float bfhi(unsigned int u) {
    return __uint_as_float(u & 0xffff0000u);
}

// ---- CSR build ----
__global__ __launch_bounds__(256) void kA_count(const int* __restrict__ dst,
                                                int* __restrict__ gcount) {
    __shared__ int cnt[256];
    int t = threadIdx.x, blk = blockIdx.x;
    cnt[t] = 0;
    __syncthreads();
    int beg = blk * CPB, end = beg + CPB;
    for (int i = beg + t; i < end; i += 256) atomicAdd(&cnt[dst[i] >> 9], 1);
    __syncthreads();
    if (t < NBUCK) gcount[t * NBLKP + blk] = cnt[t];
}

__global__ void k_scan1(const int* __restrict__ cnt, int* __restrict__ ro,
                        int* __restrict__ bsum, int n) {
    __shared__ int ts[256];
    int base = blockIdx.x * 1024 + threadIdx.x * 4;
    int v[4], s = 0;
#pragma unroll
    for (int k = 0; k < 4; ++k) {
        int idx = base + k;
        v[k] = (idx < n) ? cnt[idx] : 0;
        s += v[k];
    }
    ts[threadIdx.x] = s;
    __syncthreads();
    for (int off = 1; off < 256; off <<= 1) {
        int t = (threadIdx.x >= off) ? ts[threadIdx.x - off] : 0;
        __syncthreads();
        ts[threadIdx.x] += t;
        __syncthreads();
    }
    int ex = ts[threadIdx.x] - s;
    if (threadIdx.x == 255) bsum[blockIdx.x] = ts[255];
#pragma unroll
    for (int k = 0; k < 4; ++k) {
        int idx = base + k;
        if (idx < n) ro[idx] = ex;
        ex += v[k];
    }
}

__global__ void k_scan2(int* __restrict__ bsum, int nb) {
    __shared__ int ts[128];
    int i = threadIdx.x;
    int v = (i < nb) ? bsum[i] : 0;
    ts[i] = v;
    __syncthreads();
    for (int off = 1; off < 128; off <<= 1) {
        int t = (i >= off) ? ts[i - off] : 0;
        __syncthreads();
        ts[i] += t;
        __syncthreads();
    }
    if (i < nb) bsum[i] = ts[i] - v;
}

__global__ void k_scan3g(int* __restrict__ goff, const int* __restrict__ bsum, int n) {
    int i = blockIdx.x * 256 + threadIdx.x;
    if (i < n) goff[i] += bsum[i >> 10];
}

__global__ __launch_bounds__(256) void kB_part(const int* __restrict__ src,
                                               const int* __restrict__ dst,
                                               const int* __restrict__ goff,
                                               int* __restrict__ tmp) {
    __shared__ int cur[NBUCK];
    int t = threadIdx.x, blk = blockIdx.x;
    if (t < NBUCK) cur[t] = goff[t * NBLKP + blk];
    __syncthreads();
    int beg = blk * CPB, end = beg + CPB;
    for (int i = beg + t; i < end; i += 256) {
        int d = dst[i];
        int pos = atomicAdd(&cur[d >> 9], 1);
        tmp[pos] = ((d & 511) << 17) | src[i];
    }
}

__global__ __launch_bounds__(256) void kC_build(const int* __restrict__ goff,
                                                int* __restrict__ tmp,
                                                int* __restrict__ ss,
                                                int* __restrict__ ro,
                                                float* __restrict__ rdeg, int E) {
    __shared__ int cnt[512];
    __shared__ int ts[256];
    __shared__ int cur[512];
    int t = threadIdx.x, b = blockIdx.x;
    int beg = goff[b * NBLKP];
    int end = (b + 1 < NBUCK) ? goff[(b + 1) * NBLKP] : E;
    cnt[t] = 0;
    cnt[t + 256] = 0;
    __syncthreads();
    for (int i = beg + t; i < end; i += 256) atomicAdd(&cnt[tmp[i] >> 17], 1);
    __syncthreads();
    int a0 = cnt[2 * t], a1 = cnt[2 * t + 1], s = a0 + a1;
    ts[t] = s;
    __syncthreads();
    for (int off = 1; off < 256; off <<= 1) {
        int v = (t >= off) ? ts[t - off] : 0;
        __syncthreads();
        ts[t] += v;
        __syncthreads();
    }
    int ex = ts[t] - s;
    int p0 = beg + ex, p1 = beg + ex + a0;
    cur[2 * t] = p0;
    cur[2 * t + 1] = p1;
    int node0 = (b << 9) + 2 * t;
    if (node0 < NN) { ro[node0] = p0; rdeg[node0] = rsqrtf((float)a0 + 1.f); }
    else if (node0 == NN) ro[NN] = p0;
    int node1 = node0 + 1;
    if (node1 < NN) { ro[node1] = p1; rdeg[node1] = rsqrtf((float)a1 + 1.f); }
    else if (node1 == NN) ro[NN] = p1;
    __syncthreads();
    for (int i = beg + t; i < end; i += 256) {
        int p = tmp[i];
        int pos = atomicAdd(&cur[p >> 17], 1);
        ss[pos] = p & 0x1FFFF;
    }
}

// ---- MFMA GEMM: 64-row tile, 256 threads (4 waves), wave w -> rows [16w,16w+16).
template<int K, bool BN>
__global__ __launch_bounds__(256) void k_gemm_mfma(const float* __restrict__ Xf,
                                                   const unsigned short* __restrict__ Xh,
                                                   const float* __restrict__ W,
                                                   const float* __restrict__ bias,
                                                   const float* __restrict__ rdeg,
                                                   const float* __restrict__ stats,
                                                   const float* __restrict__ g,
                                                   const float* __restrict__ be,
                                                   unsigned short* __restrict__ Hs, int n) {
    constexpr int KB = K / 32;       // k-steps
    constexpr int RB = K * 2;        // LDS row bytes (bf16)
    __shared__ __align__(16) char raw[64 * 68 * 4];  // stage bf16[64][K] / out f32[64][68]
    __shared__ float sa_l[64], sb_l[64];
    const int t = threadIdx.x;
    const int w = t >> 6;
    const int c = t & 15;            // lane&15
    const int gq = (t >> 4) & 3;     // lane>>4
    const int r0 = blockIdx.x * 64;

    if (BN && t < 64) {
        float n_ = (float)NN;
        float mu = stats[t] / n_;
        float var = stats[64 + t] / n_ - mu * mu;
        float a = g[t] * rsqrtf(var + 1e-5f);
        sa_l[t] = a;
        sb_l[t] = be[t] - mu * a;
    }

    // W fragments: b-operand, lane c = output channel 16n+c, elems over k.
    bf16x8 wf[4][KB];
#pragma unroll
    for (int nn_ = 0; nn_ < 4; ++nn_) {
        const float* wr = W + (size_t)(16 * nn_ + c) * K;
#pragma unroll
        for (int kb = 0; kb < KB; ++kb) {
            bf16x8 v;
#pragma unroll
            for (int i = 0; i < 8; ++i) {
                int k = kb * 32 + 4 * gq + (i & 3) + 16 * (i >> 2);
                v[i] = (short)f2bf(wr[k]);
            }
            wf[nn_][kb] = v;
        }
    }
    __syncthreads();  // sa_l ready (and stage buffer free)

    // Stage X tile: thread t handles row r=t>>2, channel chunk q=t&3.
    {
        int r = t >> 2, q = t & 3;
        int row = r0 + r;
        int x_swz = (r & 7) << 4;
        if (BN) {                     // K==64: 16 ch per thread from bf16 V
            int ch0 = q * 16;
            uint4 u0 = make_uint4(0, 0, 0, 0), u1 = make_uint4(0, 0, 0, 0);
            if (row < n) {
                const uint4* p = (const uint4*)(Xh + (size_t)row * 64 + ch0);
                u0 = p[0];
                u1 = p[1];
            }
            unsigned int uin[8] = {u0.x, u0.y, u0.z, u0.w, u1.x, u1.y, u1.z, u1.w};
            unsigned int uo[8];
#pragma unroll
            for (int j = 0; j < 8; ++j) {
                int chl = ch0 + 2 * j, chh = chl + 1;
                float v0 = fmaxf(fmaf(sa_l[chl], bflo(uin[j]), sb_l[chl]), 0.f);
                float v1 = fmaxf(fmaf(sa_l[chh], bfhi(uin[j]), sb_l[chh]), 0.f);
                uo[j] = (unsigned int)f2bf(v0) | ((unsigned int)f2bf(v1) << 16);
            }
            int b0 = r * RB + q * 32;
            *(uint4*)(raw + ((b0) ^ x_swz)) = make_uint4(uo[0], uo[1], uo[2], uo[3]);
            *(uint4*)(raw + ((b0 + 16) ^ x_swz)) = make_uint4(uo[4], uo[5], uo[6], uo[7]);
        } else {                      // K==128: 32 ch per thread from f32 x
            int ch0 = q * 32;
#pragma unroll
            for (int j2 = 0; j2 < 4; ++j2) {
                float4 a = make_float4(0.f, 0.f, 0.f, 0.f), b = make_float4(0.f, 0.f, 0.f, 0.f);
                if (row < n) {
                    const float4* p = (const float4*)(Xf + (size_t)row * K + ch0 + j2 * 8);
                    a = p[0];
                    b = p[1];
                }
                unsigned int q0 = (unsigned int)f2bf(a.x) | ((unsigned int)f2bf(a.y) << 16);
                unsigned int q1 = (unsigned int)f2bf(a.z) | ((unsigned int)f2bf(a.w) << 16);
                unsigned int q2 = (unsigned int)f2bf(b.x) | ((unsigned int)f2bf(b.y) << 16);
                unsigned int q3 = (unsigned int)f2bf(b.z) | ((unsigned int)f2bf(b.w) << 16);
                int b0 = r * RB + ch0 * 2 + j2 * 16;
                *(uint4*)(raw + (b0 ^ x_swz)) = make_uint4(q0, q1, q2, q3);
            }
        }
    }
    __syncthreads();

    // A fragments from LDS + MFMA.
    bf16x8 af[KB];
    {
        int r = 16 * w + c;
        int rb = r * RB;
        int swz = (r & 7) << 4;
#pragma unroll
        for (int kb = 0; kb < KB; ++kb) {
            int off = rb + kb * 64 + gq * 8;
            uint2 u0 = *(const uint2*)(raw + (off ^ swz));
            uint2 u1 = *(const uint2*)(raw + ((off + 32) ^ swz));
            union { uint4 u; bf16x8 v; } cv;
            cv.u = make_uint4(u0.x, u0.y, u1.x, u1.y);
            af[kb] = cv.v;
        }
    }
    f32x4 acc[4];
#pragma unroll
    for (int nn_ = 0; nn_ < 4; ++nn_) {
        acc[nn_] = (f32x4){0.f, 0.f, 0.f, 0.f};
#pragma unroll
        for (int kb = 0; kb < KB; ++kb)
            acc[nn_] = __builtin_amdgcn_mfma_f32_16x16x32_bf16(af[kb], wf[nn_][kb], acc[nn_], 0, 0, 0);
    }

    // Epilogue: (acc + bias) * rdeg -> LDS f32 [64][68] -> coalesced bf16 store.
    __syncthreads();
    float* outb = (float*)raw;
    float rv[4];
#pragma unroll
    for (int i = 0; i < 4; ++i) {
        int rg = r0 + 16 * w + 4 * gq + i;
        rv[i] = (rg < n) ? rdeg[rg] : 0.f;
    }
#pragma unroll
    for (int nn_ = 0; nn_ < 4; ++nn_) {
        int col = 16 * nn_ + c;
        float bz = bias[col];
#pragma unroll
        for (int i = 0; i < 4; ++i)
            outb[(16 * w + 4 * gq + i) * 68 + col] = (acc[nn_][i] + bz) * rv[i];
    }
    __syncthreads();
    {
        int r = t >> 2, q = t & 3;
        int row = r0 + r;
        if (row < n) {
            const float* src = outb + r * 68 + q * 16;
            unsigned int u[8];
#pragma unroll
            for (int j = 0; j < 8; ++j)
                u[j] = (unsigned int)f2bf(src[2 * j]) | ((unsigned int)f2bf(src[2 * j + 1]) << 16);
            uint4* p = (uint4*)(Hs + (size_t)row * HF + q * 16);
            p[0] = make_uint4(u[0], u[1], u[2], u[3]);
            p[1] = make_uint4(u[4], u[5], u[6], u[7]);
        }
    }
}

// Aggregation: quarter-wave per node (16 lanes x 4 ch via uint2), 4 nodes/wave.
// Branch-free 16-deep batches: safe-index + mask -> all 16 gathers issue in one
// basic block (MLP), masked FMA accumulate.
__global__ __launch_bounds__(256) void k_agg(const int* __restrict__ ro,
                                             const int* __restrict__ ss,
                                             const unsigned short* __restrict__ Hs,
                                             const float* __restrict__ rdeg,
                                             unsigned short* __restrict__ V16, int n) {
    int wid = blockIdx.x * 4 + (threadIdx.x >> 6);
    int lane = threadIdx.x & 63;
    int sub = lane >> 4;           // quarter id (node slot)
    int lq = lane & 15;            // lane within quarter
    int c4 = lq * 4;               // 4 channels per lane
    int node = wid * 4 + sub;
    bool vn = node < n;
    int safe = vn ? node : 0;
    int beg = 0, d = 0;
    if (vn) {
        beg = ro[node];
        d = ro[node + 1] - beg;
    }
    float4 acc = make_float4(0.f, 0.f, 0.f, 0.f);
    if (vn) {
        uint2 u = *(const uint2*)(Hs + ((size_t)node << 6) + c4);
        acc.x = bflo(u.x); acc.y = bfhi(u.x); acc.z = bflo(u.y); acc.w = bfhi(u.y);
    }
    // wave-uniform max degree (d uniform within quarter)
    int dm = d;
    dm = max(dm, __shfl_xor(dm, 16));
    dm = max(dm, __shfl_xor(dm, 32));
    for (int it = 0; it < dm; it += 16) {
        int myidx = (it + lq < d) ? ss[beg + it + lq] : -1;
        int sidx[16];
        float msk[16];
#pragma unroll
        for (int k = 0; k < 16; ++k) {
            int s = __shfl(myidx, (sub << 4) + k);
            sidx[k] = (s >= 0) ? s : safe;
            msk[k] = (s >= 0) ? 1.f : 0.f;
        }
        uint2 u[16];
#pragma unroll
        for (int k = 0; k < 16; ++k)
            u[k] = *(const uint2*)(Hs + ((size_t)sidx[k] << 6) + c4);
#pragma unroll
        for (int k = 0; k < 16; ++k) {
            acc.x = fmaf(msk[k], bflo(u[k].x), acc.x);
            acc.y = fmaf(msk[k], bfhi(u[k].x), acc.y);
            acc.z = fmaf(msk[k], bflo(u[k].y), acc.z);
            acc.w = fmaf(msk[k], bfhi(u[k].y), acc.w);
        }
    }
    if (vn) {
        float rv = rdeg[node];
        unsigned int p0 = (unsigned int)f2bf(acc.x * rv) | ((unsigned int)f2bf(acc.y * rv) << 16);
        unsigned int p1 = (unsigned int)f2bf(acc.z * rv) | ((unsigned int)f2bf(acc.w * rv) << 16);
        *(uint2*)(V16 + ((size_t)node << 6) + c4) = make_uint2(p0, p1);
    }
}

__global__ void k_stats(const unsigned short* __restrict__ V16,
                        float* __restrict__ statsOut, int n) {
    __shared__ float ls[4][HF], lq[4][HF];
    int c = threadIdx.x & 63, w = threadIdx.x >> 6;
    float s = 0.f, q = 0.f;
    for (int r = blockIdx.x * 4 + w; r < n; r += gridDim.x * 4) {
        float v = bf2f(V16[(size_t)r * HF + c]);
        s += v;
        q += v * v;
    }
    ls[w][c] = s;
    lq[w][c] = q;
    __syncthreads();
    if (w == 0) {
        atomicAdd(&statsOut[c], ls[0][c] + ls[1][c] + ls[2][c] + ls[3][c]);
        atomicAdd(&statsOut[HF + c], lq[0][c] + lq[1][c] + lq[2][c] + lq[3][c]);
    }
}

// Pool: wave per 64 consecutive rows, run-flush atomics at graph boundaries.
__global__ __launch_bounds__(256) void k_pool2(const unsigned short* __restrict__ V16,
                                               const float* __restrict__ stats,
                                               const float* __restrict__ g,
                                               const float* __restrict__ be,
                                               const int* __restrict__ batch,
                                               float* __restrict__ pool, int n) {
    __shared__ float sa_l[64], sb_l[64];
    int t = threadIdx.x;
    if (t < 64) {
        float n_ = (float)NN;
        float mu = stats[t] / n_;
        float var = stats[64 + t] / n_ - mu * mu;
        float a = g[t] * rsqrtf(var + 1e-5f);
        sa_l[t] = a;
        sb_l[t] = be[t] - mu * a;
    }
    __syncthreads();
    int wid = blockIdx.x * 4 + (t >> 6);
    int r0 = wid * 64;
    if (r0 >= n) return;
    int lane = t & 63;
    float sa = sa_l[lane], sb = sb_l[lane];
    int rend = min(r0 + 64, n);
    int cur = batch[r0];
    float s = 0.f;
    for (int r = r0; r < rend; ++r) {
        int b = batch[r];
        if (b != cur) {
            atomicAdd(&pool[(size_t)cur * HF + lane], s);
            s = 0.f;
            cur = b;
        }
        float v = bf2f(V16[(size_t)r * HF + lane]);
        s += fmaxf(fmaf(sa, v, sb), 0.f);
    }
    atomicAdd(&pool[(size_t)cur * HF + lane], s);
}

__global__ void k_cls(const float* __restrict__ pool, const float* __restrict__ Wc1,
                      const float* __restrict__ bc1, const float* __restrict__ Wc2,
                      const float* __restrict__ bc2, float* __restrict__ out) {
    __shared__ float pl[HF], hr[HF];
    int g = blockIdx.x, c = threadIdx.x;
    pl[c] = pool[g * HF + c];
    __syncthreads();
    float h = bc1[c];
#pragma unroll
    for (int k = 0; k < HF; ++k) h = fmaf(pl[k], Wc1[c * HF + k], h);
    hr[c] = fmaxf(h, 0.f);
    __syncthreads();
    if (c < OUTF) {
        float o = bc2[c];
#pragma unroll
        for (int k = 0; k < HF; ++k) o = fmaf(hr[k], Wc2[c * HF + k], o);
        out[g * OUTF + c] = o;
    }
}

extern "C" void kernel_launch(void* const* d_in, const int* in_sizes, int n_in,
                              void* d_out, int out_size, void* d_ws, size_t ws_size,
                              hipStream_t stream) {
    const float* x = (const float*)d_in[0];
    const int* edge = (const int*)d_in[1];
    const int* batch = (const int*)d_in[2];
    const float* W1 = (const float*)d_in[3];
    const float* b1 = (const float*)d_in[4];
    const float* g1 = (const float*)d_in[5];
    const float* be1 = (const float*)d_in[6];
    const float* W2 = (const float*)d_in[7];
    const float* b2 = (const float*)d_in[8];
    const float* g2 = (const float*)d_in[9];
    const float* be2 = (const float*)d_in[10];
    const float* W3 = (const float*)d_in[11];
    const float* b3 = (const float*)d_in[12];
    const float* g3 = (const float*)d_in[13];
    const float* be3 = (const float*)d_in[14];
    const float* Wc1 = (const float*)d_in[15];
    const float* bc1 = (const float*)d_in[16];
    const float* Wc2 = (const float*)d_in[17];
    const float* bc2 = (const float*)d_in[18];
    float* out = (float*)d_out;

    const int* src = edge;
    const int* dst = edge + NE;

    const size_t N64 = (size_t)NN * HF;
    const int NGC = NBUCK * NBLKP;                       // 25088
    unsigned short* V16 = (unsigned short*)d_ws;         // N*64 bf16
    unsigned short* Hs = V16 + N64;                      // N*64 bf16
    float* rdeg = (float*)(Hs + N64);                    // N
    float* stats = rdeg + NN;                            // 3*128 (per-layer sum|sumsq)
    float* pool = stats + 384;                           // NG*64 (contiguous w/ stats)
    int* gcount = (int*)(pool + (size_t)NG * HF);        // NGC
    int* goff = gcount + NGC;                            // NGC
    int* bsum = goff + NGC;                              // 128
    int* ro = bsum + 128;                                // N+1
    int* tmp = ro + NN + 1;                              // E
    int* ss = tmp + NE;                                  // E

    // ---- CSR build (2-level bucket sort) ----
    kA_count<<<NBLKP, 256, 0, stream>>>(dst, gcount);
    const int nblk = (NGC + 1023) / 1024;                // 25
    k_scan1<<<nblk, 256, 0, stream>>>(gcount, goff, bsum, NGC);
    k_scan2<<<1, 128, 0, stream>>>(bsum, nblk);
    k_scan3g<<<(NGC + 255) / 256, 256, 0, stream>>>(goff, bsum, NGC);
    kB_part<<<NBLKP, 256, 0, stream>>>(src, dst, goff, tmp);
    kC_build<<<NBUCK, 256, 0, stream>>>(goff, tmp, ss, ro, rdeg, NE);

    // one memset covers stats[3][128] + pool
    hipMemsetAsync(stats, 0, (384 + (size_t)NG * HF) * sizeof(float), stream);

    const float* gW[3] = {W1, W2, W3};
    const float* gb[3] = {b1, b2, b3};
    const float* gg[3] = {g1, g2, g3};
    const float* gbe[3] = {be1, be2, be3};

    const int tileblk = (NN + 63) / 64;
    const int aggblk = (NN + 15) / 16;        // 4 nodes/wave * 4 waves
    const int poolblk = ((NN + 63) / 64 + 3) / 4;

    for (int l = 0; l < 3; ++l) {
        if (l == 0)
            k_gemm_mfma<INF_, false><<<tileblk, 256, 0, stream>>>(x, (const unsigned short*)0,
                                                                  gW[0], gb[0], rdeg, stats,
                                                                  gg[0], gbe[0], Hs, NN);
        else
            k_gemm_mfma<HF, true><<<tileblk, 256, 0, stream>>>((const float*)0, V16,
                                                               gW[l], gb[l], rdeg,
                                                               stats + 128 * (l - 1),
                                                               gg[l - 1], gbe[l - 1], Hs, NN);
        k_agg<<<aggblk, 256, 0, stream>>>(ro, ss, Hs, rdeg, V16, NN);
        k_stats<<<1024, 256, 0, stream>>>(V16, stats + 128 * l, NN);
        if (l == 2)
            k_pool2<<<poolblk, 256, 0, stream>>>(V16, stats + 256, gg[2], gbe[2], batch, pool, NN);
    }

    k_cls<<<NG, HF, 0, stream>>>(pool, Wc1, bc1, Wc2, bc2, out);
}

// Round 10
// 322.444 us; speedup vs baseline: 2.9615x; 1.1595x over previous
//
#include <hip/hip_runtime.h>
#include <hip/hip_bf16.h>

// GCN graph classifier: 3x (GCNConv -> BN -> ReLU) -> sum-pool -> MLP head.
//   Hs[i] = (relu_bn(x[i])@W.T + b) * rdeg[i]   (MFMA bf16 gemm, packed-W frags, BN fused)
//   V[d]  = rdeg[d]*(Hs[d] + sum_in Hs[s])      (CSR gather; branch-free 16-deep MLP; bf16 out)
// CSR via 2-level bucket sort (line-dense writes, LDS atomics only).
// Pool = run-flush segmented sum over sorted batch (wave per 64 rows).

#define NN 100000
#define NE 1600000
#define INF_ 128
#define HF 64
#define OUTF 10
#define NG 128
#define NBUCK 196     // ceil(NN/512)
#define NBLKP 512     // partition blocks; NE % NBLKP == 0 -> 3125 edges/block
#define CPB (NE / NBLKP)

typedef short bf16x8 __attribute__((ext_vector_type(8)));
typedef float f32x4 __attribute__((ext_vector_type(4)));

static __device__ __forceinline__ unsigned short f2bf(float x) {
    unsigned int b = __float_as_uint(x);
    b += 0x7FFFu + ((b >> 16) & 1u);   // RNE
    return (unsigned short)(b >> 16);
}
static __device__ __forceinline__ float bf2f(unsigned short u) {
    return __uint_as_float(((unsigned int)u) << 16);
}
static __device__ __forceinline__ float bflo(unsigned int u) {
    return __uint_as_float(u << 16);
}
static __device__ __forceinline__ float bfhi(unsigned int u) {
    return __uint_as_float(u & 0xffff0000u);
}

// ---- CSR build ----
__global__ __launch_bounds__(256) void kA_count(const int* __restrict__ dst,
                                                int* __restrict__ gcount) {
    __shared__ int cnt[256];
    int t = threadIdx.x, blk = blockIdx.x;
    cnt[t] = 0;
    __syncthreads();
    int beg = blk * CPB, end = beg + CPB;
    for (int i = beg + t; i < end; i += 256) atomicAdd(&cnt[dst[i] >> 9], 1);
    __syncthreads();
    if (t < NBUCK) gcount[t * NBLKP + blk] = cnt[t];
}

__global__ void k_scan1(const int* __restrict__ cnt, int* __restrict__ ro,
                        int* __restrict__ bsum, int n) {
    __shared__ int ts[256];
    int base = blockIdx.x * 1024 + threadIdx.x * 4;
    int v[4], s = 0;
#pragma unroll
    for (int k = 0; k < 4; ++k) {
        int idx = base + k;
        v[k] = (idx < n) ? cnt[idx] : 0;
        s += v[k];
    }
    ts[threadIdx.x] = s;
    __syncthreads();
    for (int off = 1; off < 256; off <<= 1) {
        int t = (threadIdx.x >= off) ? ts[threadIdx.x - off] : 0;
        __syncthreads();
        ts[threadIdx.x] += t;
        __syncthreads();
    }
    int ex = ts[threadIdx.x] - s;
    if (threadIdx.x == 255) bsum[blockIdx.x] = ts[255];
#pragma unroll
    for (int k = 0; k < 4; ++k) {
        int idx = base + k;
        if (idx < n) ro[idx] = ex;
        ex += v[k];
    }
}

__global__ void k_scan2(int* __restrict__ bsum, int nb) {
    __shared__ int ts[128];
    int i = threadIdx.x;
    int v = (i < nb) ? bsum[i] : 0;
    ts[i] = v;
    __syncthreads();
    for (int off = 1; off < 128; off <<= 1) {
        int t = (i >= off) ? ts[i - off] : 0;
        __syncthreads();
        ts[i] += t;
        __syncthreads();
    }
    if (i < nb) bsum[i] = ts[i] - v;
}

__global__ void k_scan3g(int* __restrict__ goff, const int* __restrict__ bsum, int n) {
    int i = blockIdx.x * 256 + threadIdx.x;
    if (i < n) goff[i] += bsum[i >> 10];
}

__global__ __launch_bounds__(256) void kB_part(const int* __restrict__ src,
                                               const int* __restrict__ dst,
                                               const int* __restrict__ goff,
                                               int* __restrict__ tmp) {
    __shared__ int cur[NBUCK];
    int t = threadIdx.x, blk = blockIdx.x;
    if (t < NBUCK) cur[t] = goff[t * NBLKP + blk];
    __syncthreads();
    int beg = blk * CPB, end = beg + CPB;
    for (int i = beg + t; i < end; i += 256) {
        int d = dst[i];
        int pos = atomicAdd(&cur[d >> 9], 1);
        tmp[pos] = ((d & 511) << 17) | src[i];
    }
}

__global__ __launch_bounds__(256) void kC_build(const int* __restrict__ goff,
                                                int* __restrict__ tmp,
                                                int* __restrict__ ss,
                                                int* __restrict__ ro,
                                                float* __restrict__ rdeg, int E) {
    __shared__ int cnt[512];
    __shared__ int ts[256];
    __shared__ int cur[512];
    int t = threadIdx.x, b = blockIdx.x;
    int beg = goff[b * NBLKP];
    int end = (b + 1 < NBUCK) ? goff[(b + 1) * NBLKP] : E;
    cnt[t] = 0;
    cnt[t + 256] = 0;
    __syncthreads();
    for (int i = beg + t; i < end; i += 256) atomicAdd(&cnt[tmp[i] >> 17], 1);
    __syncthreads();
    int a0 = cnt[2 * t], a1 = cnt[2 * t + 1], s = a0 + a1;
    ts[t] = s;
    __syncthreads();
    for (int off = 1; off < 256; off <<= 1) {
        int v = (t >= off) ? ts[t - off] : 0;
        __syncthreads();
        ts[t] += v;
        __syncthreads();
    }
    int ex = ts[t] - s;
    int p0 = beg + ex, p1 = beg + ex + a0;
    cur[2 * t] = p0;
    cur[2 * t + 1] = p1;
    int node0 = (b << 9) + 2 * t;
    if (node0 < NN) { ro[node0] = p0; rdeg[node0] = rsqrtf((float)a0 + 1.f); }
    else if (node0 == NN) ro[NN] = p0;
    int node1 = node0 + 1;
    if (node1 < NN) { ro[node1] = p1; rdeg[node1] = rsqrtf((float)a1 + 1.f); }
    else if (node1 == NN) ro[NN] = p1;
    __syncthreads();
    for (int i = beg + t; i < end; i += 256) {
        int p = tmp[i];
        int pos = atomicAdd(&cur[p >> 17], 1);
        ss[pos] = p & 0x1FFFF;
    }
}

// ---- W fragment pre-pack: W[64][K] f32 -> pack[(kb*4+gq)*64 + ch][8] bf16,
// elem i of chunk = W[ch][kb*32 + 4*gq + (i&3) + 16*(i>>2)].
__global__ void k_wpack(const float* __restrict__ W, unsigned short* __restrict__ pack, int K) {
    int q = blockIdx.x * 256 + threadIdx.x;
    int nchunk = (K >> 5) << 8;   // (K/32)*4*64
    if (q >= nchunk) return;
    int kb = q >> 8;
    int gq = (q >> 6) & 3;
    int ch = q & 63;
    const float* wr = W + (size_t)ch * K;
    unsigned int u[4];
#pragma unroll
    for (int i = 0; i < 4; ++i) {
        int e0 = 2 * i, e1 = 2 * i + 1;
        int k0 = kb * 32 + 4 * gq + (e0 & 3) + 16 * (e0 >> 2);
        int k1 = kb * 32 + 4 * gq + (e1 & 3) + 16 * (e1 >> 2);
        u[i] = (unsigned int)f2bf(wr[k0]) | ((unsigned int)f2bf(wr[k1]) << 16);
    }
    *(uint4*)(pack + (size_t)q * 8) = make_uint4(u[0], u[1], u[2], u[3]);
}

// ---- MFMA GEMM: 64-row tile, 256 threads (4 waves), wave w -> rows [16w,16w+16).
// W fragments from packed buffer: one coalesced uint4 per (nn,kb).
template<int K, bool BN>
__global__ __launch_bounds__(256) void k_gemm_mfma(const float* __restrict__ Xf,
                                                   const unsigned short* __restrict__ Xh,
                                                   const unsigned short* __restrict__ Wp,
                                                   const float* __restrict__ bias,
                                                   const float* __restrict__ rdeg,
                                                   const float* __restrict__ stats,
                                                   const float* __restrict__ g,
                                                   const float* __restrict__ be,
                                                   unsigned short* __restrict__ Hs, int n) {
    constexpr int KB = K / 32;       // k-steps
    constexpr int RB = K * 2;        // LDS row bytes (bf16)
    __shared__ __align__(16) char raw[64 * 68 * 4];  // stage bf16[64][K] / out f32[64][68]
    __shared__ float sa_l[64], sb_l[64];
    const int t = threadIdx.x;
    const int w = t >> 6;
    const int c = t & 15;            // lane&15
    const int gq = (t >> 4) & 3;     // lane>>4
    const int r0 = blockIdx.x * 64;

    if (BN && t < 64) {
        float n_ = (float)NN;
        float mu = stats[t] / n_;
        float var = stats[64 + t] / n_ - mu * mu;
        float a = g[t] * rsqrtf(var + 1e-5f);
        sa_l[t] = a;
        sb_l[t] = be[t] - mu * a;
    }
    __syncthreads();  // sa_l ready

    // Stage X tile: thread t handles row r=t>>2, channel chunk q=t&3.
    {
        int r = t >> 2, q = t & 3;
        int row = r0 + r;
        int x_swz = (r & 7) << 4;
        if (BN) {                     // K==64: 16 ch per thread from bf16 V
            int ch0 = q * 16;
            uint4 u0 = make_uint4(0, 0, 0, 0), u1 = make_uint4(0, 0, 0, 0);
            if (row < n) {
                const uint4* p = (const uint4*)(Xh + (size_t)row * 64 + ch0);
                u0 = p[0];
                u1 = p[1];
            }
            unsigned int uin[8] = {u0.x, u0.y, u0.z, u0.w, u1.x, u1.y, u1.z, u1.w};
            unsigned int uo[8];
#pragma unroll
            for (int j = 0; j < 8; ++j) {
                int chl = ch0 + 2 * j, chh = chl + 1;
                float v0 = fmaxf(fmaf(sa_l[chl], bflo(uin[j]), sb_l[chl]), 0.f);
                float v1 = fmaxf(fmaf(sa_l[chh], bfhi(uin[j]), sb_l[chh]), 0.f);
                uo[j] = (unsigned int)f2bf(v0) | ((unsigned int)f2bf(v1) << 16);
            }
            int b0 = r * RB + q * 32;
            *(uint4*)(raw + ((b0) ^ x_swz)) = make_uint4(uo[0], uo[1], uo[2], uo[3]);
            *(uint4*)(raw + ((b0 + 16) ^ x_swz)) = make_uint4(uo[4], uo[5], uo[6], uo[7]);
        } else {                      // K==128: 32 ch per thread from f32 x
            int ch0 = q * 32;
#pragma unroll
            for (int j2 = 0; j2 < 4; ++j2) {
                float4 a = make_float4(0.f, 0.f, 0.f, 0.f), b = make_float4(0.f, 0.f, 0.f, 0.f);
                if (row < n) {
                    const float4* p = (const float4*)(Xf + (size_t)row * K + ch0 + j2 * 8);
                    a = p[0];
                    b = p[1];
                }
                unsigned int q0 = (unsigned int)f2bf(a.x) | ((unsigned int)f2bf(a.y) << 16);
                unsigned int q1 = (unsigned int)f2bf(a.z) | ((unsigned int)f2bf(a.w) << 16);
                unsigned int q2 = (unsigned int)f2bf(b.x) | ((unsigned int)f2bf(b.y) << 16);
                unsigned int q3 = (unsigned int)f2bf(b.z) | ((unsigned int)f2bf(b.w) << 16);
                int b0 = r * RB + ch0 * 2 + j2 * 16;
                *(uint4*)(raw + (b0 ^ x_swz)) = make_uint4(q0, q1, q2, q3);
            }
        }
    }
    __syncthreads();

    // A fragments from LDS + MFMA with packed-W loads.
    bf16x8 af[KB];
    {
        int r = 16 * w + c;
        int rb = r * RB;
        int swz = (r & 7) << 4;
#pragma unroll
        for (int kb = 0; kb < KB; ++kb) {
            int off = rb + kb * 64 + gq * 8;
            uint2 u0 = *(const uint2*)(raw + (off ^ swz));
            uint2 u1 = *(const uint2*)(raw + ((off + 32) ^ swz));
            union { uint4 u; bf16x8 v; } cv;
            cv.u = make_uint4(u0.x, u0.y, u1.x, u1.y);
            af[kb] = cv.v;
        }
    }
    const uint4* wq = (const uint4*)Wp;
    f32x4 acc[4];
#pragma unroll
    for (int nn_ = 0; nn_ < 4; ++nn_) {
        acc[nn_] = (f32x4){0.f, 0.f, 0.f, 0.f};
#pragma unroll
        for (int kb = 0; kb < KB; ++kb) {
            union { uint4 u; bf16x8 v; } cw;
            cw.u = wq[(kb * 4 + gq) * 64 + nn_ * 16 + c];
            acc[nn_] = __builtin_amdgcn_mfma_f32_16x16x32_bf16(af[kb], cw.v, acc[nn_], 0, 0, 0);
        }
    }

    // Epilogue: (acc + bias) * rdeg -> LDS f32 [64][68] -> coalesced bf16 store.
    __syncthreads();
    float* outb = (float*)raw;
    float rv[4];
#pragma unroll
    for (int i = 0; i < 4; ++i) {
        int rg = r0 + 16 * w + 4 * gq + i;
        rv[i] = (rg < n) ? rdeg[rg] : 0.f;
    }
#pragma unroll
    for (int nn_ = 0; nn_ < 4; ++nn_) {
        int col = 16 * nn_ + c;
        float bz = bias[col];
#pragma unroll
        for (int i = 0; i < 4; ++i)
            outb[(16 * w + 4 * gq + i) * 68 + col] = (acc[nn_][i] + bz) * rv[i];
    }
    __syncthreads();
    {
        int r = t >> 2, q = t & 3;
        int row = r0 + r;
        if (row < n) {
            const float* src = outb + r * 68 + q * 16;
            unsigned int u[8];
#pragma unroll
            for (int j = 0; j < 8; ++j)
                u[j] = (unsigned int)f2bf(src[2 * j]) | ((unsigned int)f2bf(src[2 * j + 1]) << 16);
            uint4* p = (uint4*)(Hs + (size_t)row * HF + q * 16);
            p[0] = make_uint4(u[0], u[1], u[2], u[3]);
            p[1] = make_uint4(u[4], u[5], u[6], u[7]);
        }
    }
}

// Aggregation: quarter-wave per node (16 lanes x 4 ch via uint2), 4 nodes/wave.
// Branch-free 16-deep batches: safe-index + mask -> all 16 gathers issue together.
__global__ __launch_bounds__(256) void k_agg(const int* __restrict__ ro,
                                             const int* __restrict__ ss,
                                             const unsigned short* __restrict__ Hs,
                                             const float* __restrict__ rdeg,
                                             unsigned short* __restrict__ V16, int n) {
    int wid = blockIdx.x * 4 + (threadIdx.x >> 6);
    int lane = threadIdx.x & 63;
    int sub = lane >> 4;           // quarter id (node slot)
    int lq = lane & 15;            // lane within quarter
    int c4 = lq * 4;               // 4 channels per lane
    int node = wid * 4 + sub;
    bool vn = node < n;
    int safe = vn ? node : 0;
    int beg = 0, d = 0;
    if (vn) {
        beg = ro[node];
        d = ro[node + 1] - beg;
    }
    float4 acc = make_float4(0.f, 0.f, 0.f, 0.f);
    if (vn) {
        uint2 u = *(const uint2*)(Hs + ((size_t)node << 6) + c4);
        acc.x = bflo(u.x); acc.y = bfhi(u.x); acc.z = bflo(u.y); acc.w = bfhi(u.y);
    }
    int dm = d;
    dm = max(dm, __shfl_xor(dm, 16));
    dm = max(dm, __shfl_xor(dm, 32));
    for (int it = 0; it < dm; it += 16) {
        int myidx = (it + lq < d) ? ss[beg + it + lq] : -1;
        int sidx[16];
        float msk[16];
#pragma unroll
        for (int k = 0; k < 16; ++k) {
            int s = __shfl(myidx, (sub << 4) + k);
            sidx[k] = (s >= 0) ? s : safe;
            msk[k] = (s >= 0) ? 1.f : 0.f;
        }
        uint2 u[16];
#pragma unroll
        for (int k = 0; k < 16; ++k)
            u[k] = *(const uint2*)(Hs + ((size_t)sidx[k] << 6) + c4);
#pragma unroll
        for (int k = 0; k < 16; ++k) {
            acc.x = fmaf(msk[k], bflo(u[k].x), acc.x);
            acc.y = fmaf(msk[k], bfhi(u[k].x), acc.y);
            acc.z = fmaf(msk[k], bflo(u[k].y), acc.z);
            acc.w = fmaf(msk[k], bfhi(u[k].y), acc.w);
        }
    }
    if (vn) {
        float rv = rdeg[node];
        unsigned int p0 = (unsigned int)f2bf(acc.x * rv) | ((unsigned int)f2bf(acc.y * rv) << 16);
        unsigned int p1 = (unsigned int)f2bf(acc.z * rv) | ((unsigned int)f2bf(acc.w * rv) << 16);
        *(uint2*)(V16 + ((size_t)node << 6) + c4) = make_uint2(p0, p1);
    }
}

__global__ void k_stats(const unsigned short* __restrict__ V16,
                        float* __restrict__ statsOut, int n) {
    __shared__ float ls[4][HF], lq[4][HF];
    int c = threadIdx.x & 63, w = threadIdx.x >> 6;
    float s = 0.f, q = 0.f;
    for (int r = blockIdx.x * 4 + w; r < n; r += gridDim.x * 4) {
        float v = bf2f(V16[(size_t)r * HF + c]);
        s += v;
        q += v * v;
    }
    ls[w][c] = s;
    lq[w][c] = q;
    __syncthreads();
    if (w == 0) {
        atomicAdd(&statsOut[c], ls[0][c] + ls[1][c] + ls[2][c] + ls[3][c]);
        atomicAdd(&statsOut[HF + c], lq[0][c] + lq[1][c] + lq[2][c] + lq[3][c]);
    }
}

// Pool: wave per 64 consecutive rows, run-flush atomics at graph boundaries.
__global__ __launch_bounds__(256) void k_pool2(const unsigned short* __restrict__ V16,
                                               const float* __restrict__ stats,
                                               const float* __restrict__ g,
                                               const float* __restrict__ be,
                                               const int* __restrict__ batch,
                                               float* __restrict__ pool, int n) {
    __shared__ float sa_l[64], sb_l[64];
    int t = threadIdx.x;
    if (t < 64) {
        float n_ = (float)NN;
        float mu = stats[t] / n_;
        float var = stats[64 + t] / n_ - mu * mu;
        float a = g[t] * rsqrtf(var + 1e-5f);
        sa_l[t] = a;
        sb_l[t] = be[t] - mu * a;
    }
    __syncthreads();
    int wid = blockIdx.x * 4 + (t >> 6);
    int r0 = wid * 64;
    if (r0 >= n) return;
    int lane = t & 63;
    float sa = sa_l[lane], sb = sb_l[lane];
    int rend = min(r0 + 64, n);
    int cur = batch[r0];
    float s = 0.f;
    for (int r = r0; r < rend; ++r) {
        int b = batch[r];
        if (b != cur) {
            atomicAdd(&pool[(size_t)cur * HF + lane], s);
            s = 0.f;
            cur = b;
        }
        float v = bf2f(V16[(size_t)r * HF + lane]);
        s += fmaxf(fmaf(sa, v, sb), 0.f);
    }
    atomicAdd(&pool[(size_t)cur * HF + lane], s);
}

__global__ void k_cls(const float* __restrict__ pool, const float* __restrict__ Wc1,
                      const float* __restrict__ bc1, const float* __restrict__ Wc2,
                      const float* __restrict__ bc2, float* __restrict__ out) {
    __shared__ float pl[HF], hr[HF];
    int g = blockIdx.x, c = threadIdx.x;
    pl[c] = pool[g * HF + c];
    __syncthreads();
    float h = bc1[c];
#pragma unroll
    for (int k = 0; k < HF; ++k) h = fmaf(pl[k], Wc1[c * HF + k], h);
    hr[c] = fmaxf(h, 0.f);
    __syncthreads();
    if (c < OUTF) {
        float o = bc2[c];
#pragma unroll
        for (int k = 0; k < HF; ++k) o = fmaf(hr[k], Wc2[c * HF + k], o);
        out[g * OUTF + c] = o;
    }
}

extern "C" void kernel_launch(void* const* d_in, const int* in_sizes, int n_in,
                              void* d_out, int out_size, void* d_ws, size_t ws_size,
                              hipStream_t stream) {
    const float* x = (const float*)d_in[0];
    const int* edge = (const int*)d_in[1];
    const int* batch = (const int*)d_in[2];
    const float* W1 = (const float*)d_in[3];
    const float* b1 = (const float*)d_in[4];
    const float* g1 = (const float*)d_in[5];
    const float* be1 = (const float*)d_in[6];
    const float* W2 = (const float*)d_in[7];
    const float* b2 = (const float*)d_in[8];
    const float* g2 = (const float*)d_in[9];
    const float* be2 = (const float*)d_in[10];
    const float* W3 = (const float*)d_in[11];
    const float* b3 = (const float*)d_in[12];
    const float* g3 = (const float*)d_in[13];
    const float* be3 = (const float*)d_in[14];
    const float* Wc1 = (const float*)d_in[15];
    const float* bc1 = (const float*)d_in[16];
    const float* Wc2 = (const float*)d_in[17];
    const float* bc2 = (const float*)d_in[18];
    float* out = (float*)d_out;

    const int* src = edge;
    const int* dst = edge + NE;

    const size_t N64 = (size_t)NN * HF;
    const int NGC = NBUCK * NBLKP;                       // 100352
    unsigned short* V16 = (unsigned short*)d_ws;         // N*64 bf16
    unsigned short* Hs = V16 + N64;                      // N*64 bf16
    float* rdeg = (float*)(Hs + N64);                    // N
    float* stats = rdeg + NN;                            // 3*128 (per-layer sum|sumsq)
    float* pool = stats + 384;                           // NG*64 (contiguous w/ stats)
    int* gcount = (int*)(pool + (size_t)NG * HF);        // NGC
    int* goff = gcount + NGC;                            // NGC
    int* bsum = goff + NGC;                              // 128
    int* ro = bsum + 128;                                // N+1
    int* tmp = ro + NN + 1;                              // E
    int* ss = tmp + NE;                                  // E
    unsigned short* wp0 = (unsigned short*)(ss + NE);    // 8192 (W1 pack)
    unsigned short* wp1 = wp0 + 8192;                    // 4096 (W2 pack)
    unsigned short* wp2 = wp1 + 4096;                    // 4096 (W3 pack)

    // ---- W fragment pre-pack ----
    k_wpack<<<4, 256, 0, stream>>>(W1, wp0, INF_);
    k_wpack<<<2, 256, 0, stream>>>(W2, wp1, HF);
    k_wpack<<<2, 256, 0, stream>>>(W3, wp2, HF);

    // ---- CSR build (2-level bucket sort) ----
    kA_count<<<NBLKP, 256, 0, stream>>>(dst, gcount);
    const int nblk = (NGC + 1023) / 1024;                // 98
    k_scan1<<<nblk, 256, 0, stream>>>(gcount, goff, bsum, NGC);
    k_scan2<<<1, 128, 0, stream>>>(bsum, nblk);
    k_scan3g<<<(NGC + 255) / 256, 256, 0, stream>>>(goff, bsum, NGC);
    kB_part<<<NBLKP, 256, 0, stream>>>(src, dst, goff, tmp);
    kC_build<<<NBUCK, 256, 0, stream>>>(goff, tmp, ss, ro, rdeg, NE);

    // one memset covers stats[3][128] + pool
    hipMemsetAsync(stats, 0, (384 + (size_t)NG * HF) * sizeof(float), stream);

    const unsigned short* gWp[3] = {wp0, wp1, wp2};
    const float* gb[3] = {b1, b2, b3};
    const float* gg[3] = {g1, g2, g3};
    const float* gbe[3] = {be1, be2, be3};

    const int tileblk = (NN + 63) / 64;
    const int aggblk = (NN + 15) / 16;        // 4 nodes/wave * 4 waves
    const int poolblk = ((NN + 63) / 64 + 3) / 4;

    for (int l = 0; l < 3; ++l) {
        if (l == 0)
            k_gemm_mfma<INF_, false><<<tileblk, 256, 0, stream>>>(x, (const unsigned short*)0,
                                                                  gWp[0], gb[0], rdeg, stats,
                                                                  gg[0], gbe[0], Hs, NN);
        else
            k_gemm_mfma<HF, true><<<tileblk, 256, 0, stream>>>((const float*)0, V16,
                                                               gWp[l], gb[l], rdeg,
                                                               stats + 128 * (l - 1),
                                                               gg[l - 1], gbe[l - 1], Hs, NN);
        k_agg<<<aggblk, 256, 0, stream>>>(ro, ss, Hs, rdeg, V16, NN);
        k_stats<<<1024, 256, 0, stream>>>(V16, stats + 128 * l, NN);
        if (l == 2)
            k_pool2<<<poolblk, 256, 0, stream>>>(V16, stats + 256, gg[2], gbe[2], batch, pool, NN);
    }

    k_cls<<<NG, HF, 0, stream>>>(pool, Wc1, bc1, Wc2, bc2, out);
}